// Round 7
// baseline (4754.330 us; speedup 1.0000x reference)
//
#include <hip/hip_runtime.h>

// ---------------------------------------------------------------------------
// SFGCN forward on MI355X, round 7:
//  - fused_l1l2 v2: W staged in 16KB chunks -> 32KB LDS -> 5 blocks/CU
//    (was 48KB/3 blocks, latency-bound at 29% occupancy).
//  - spmm_dual64: one kernel gathers BOTH hw arrays (edge metadata read once),
//    lanes 0-15 -> S-chain, 16-31 -> C-chain.
//  - edge-unroll x4 in all SpMM loops (4 gathers in flight per lane).
// ---------------------------------------------------------------------------

// ---------------- CSR build ----------------

__global__ __launch_bounds__(256) void hist_kernel(
    const int* __restrict__ row, int* __restrict__ cnt, int e) {
  int i = blockIdx.x * 256 + threadIdx.x;
  if (i < e) atomicAdd(&cnt[row[i]], 1);
}

__global__ __launch_bounds__(256) void scan_partial(
    const int* __restrict__ cnt, int* __restrict__ part, int n) {
  __shared__ int red[256];
  int t = threadIdx.x;
  int base = blockIdx.x * 1024 + t * 4;
  int s = 0;
#pragma unroll
  for (int j = 0; j < 4; ++j) {
    int idx = base + j;
    if (idx < n) s += cnt[idx];
  }
  red[t] = s;
  __syncthreads();
#pragma unroll
  for (int d = 128; d > 0; d >>= 1) {
    if (t < d) red[t] += red[t + d];
    __syncthreads();
  }
  if (t == 0) part[blockIdx.x] = red[0];
}

__global__ __launch_bounds__(256) void scan_tops(int* __restrict__ part,
                                                 int nb) {
  __shared__ int lds[256];
  int t = threadIdx.x;
  lds[t] = (t < nb) ? part[t] : 0;
  __syncthreads();
#pragma unroll
  for (int d = 1; d < 256; d <<= 1) {
    int v = (t >= d) ? lds[t - d] : 0;
    __syncthreads();
    lds[t] += v;
    __syncthreads();
  }
  if (t < nb) part[t] = (t == 0) ? 0 : lds[t - 1];
}

__global__ __launch_bounds__(256) void scan_final(
    const int* __restrict__ cnt, const int* __restrict__ part,
    int* __restrict__ rowptr, int* __restrict__ woff, int n, int e) {
  __shared__ int lds[256];
  int t = threadIdx.x;
  int base = blockIdx.x * 1024 + t * 4;
  int c[4];
  int s = 0;
#pragma unroll
  for (int j = 0; j < 4; ++j) {
    int idx = base + j;
    c[j] = (idx < n) ? cnt[idx] : 0;
    s += c[j];
  }
  lds[t] = s;
  __syncthreads();
#pragma unroll
  for (int d = 1; d < 256; d <<= 1) {
    int v = (t >= d) ? lds[t - d] : 0;
    __syncthreads();
    lds[t] += v;
    __syncthreads();
  }
  int off = part[blockIdx.x] + ((t == 0) ? 0 : lds[t - 1]);
#pragma unroll
  for (int j = 0; j < 4; ++j) {
    int idx = base + j;
    if (idx < n) {
      rowptr[idx] = off;
      woff[idx] = off;
      off += c[j];
    }
  }
  if (blockIdx.x == 0 && t == 0) rowptr[n] = e;
}

__global__ __launch_bounds__(256) void scatter_kernel(
    const int* __restrict__ row, const int* __restrict__ col,
    const float* __restrict__ val, int* __restrict__ woff,
    int* __restrict__ scol, float* __restrict__ sval, int e) {
  int i = blockIdx.x * 256 + threadIdx.x;
  if (i >= e) return;
  int r = row[i];
  int p = atomicAdd(&woff[r], 1);
  scol[p] = col[i];
  sval[p] = val[i];
}

// ---------------- CSR SpMM ----------------

// 128 feats: 32 lanes/row, edge-unroll x4; output split into halves OA/OB.
__global__ __launch_bounds__(256) void spmm_csr_128(
    const int* __restrict__ rowptr, const int* __restrict__ scol,
    const float* __restrict__ sval, const float* __restrict__ h,
    float* __restrict__ OA, float* __restrict__ OB, int n) {
  int tid = threadIdx.x;
  int r = blockIdx.x * 8 + (tid >> 5);
  if (r >= n) return;
  int lane = tid & 31;
  int lo = rowptr[r], hi = rowptr[r + 1];
  const float4* h4 = (const float4*)h;
  float4 acc = make_float4(0.f, 0.f, 0.f, 0.f);
  int e = lo;
  for (; e + 4 <= hi; e += 4) {
    int c0 = scol[e], c1 = scol[e + 1], c2 = scol[e + 2], c3 = scol[e + 3];
    float v0 = sval[e], v1 = sval[e + 1], v2 = sval[e + 2], v3 = sval[e + 3];
    float4 h0 = h4[(long)c0 * 32 + lane];
    float4 h1 = h4[(long)c1 * 32 + lane];
    float4 h2 = h4[(long)c2 * 32 + lane];
    float4 h3 = h4[(long)c3 * 32 + lane];
    acc.x += v0 * h0.x + v1 * h1.x + v2 * h2.x + v3 * h3.x;
    acc.y += v0 * h0.y + v1 * h1.y + v2 * h2.y + v3 * h3.y;
    acc.z += v0 * h0.z + v1 * h1.z + v2 * h2.z + v3 * h3.z;
    acc.w += v0 * h0.w + v1 * h1.w + v2 * h2.w + v3 * h3.w;
  }
  for (; e < hi; ++e) {
    float v = sval[e];
    float4 hv = h4[(long)scol[e] * 32 + lane];
    acc.x += v * hv.x;
    acc.y += v * hv.y;
    acc.z += v * hv.z;
    acc.w += v * hv.w;
  }
  if (lane < 16)
    ((float4*)OA)[(long)r * 16 + lane] = acc;
  else
    ((float4*)OB)[(long)r * 16 + (lane - 16)] = acc;
}

// Dual 64-feat SpMM: 32 lanes/row; lanes 0-15 gather hS -> outS (+bS),
// lanes 16-31 gather hC -> outC (+bC). Edge metadata read once.
__global__ __launch_bounds__(256) void spmm_dual64(
    const int* __restrict__ rowptr, const int* __restrict__ scol,
    const float* __restrict__ sval, const float* __restrict__ hS,
    const float* __restrict__ hC, const float* __restrict__ bS,
    const float* __restrict__ bC, float* __restrict__ outS,
    float* __restrict__ outC, int n) {
  int tid = threadIdx.x;
  int r = blockIdx.x * 8 + (tid >> 5);
  if (r >= n) return;
  int lane = tid & 31;
  int half = lane >> 4;
  int li = lane & 15;
  const float4* h4 = (const float4*)(half ? hC : hS);
  float4 acc = ((const float4*)(half ? bC : bS))[li];
  int lo = rowptr[r], hi = rowptr[r + 1];
  int e = lo;
  for (; e + 4 <= hi; e += 4) {
    int c0 = scol[e], c1 = scol[e + 1], c2 = scol[e + 2], c3 = scol[e + 3];
    float v0 = sval[e], v1 = sval[e + 1], v2 = sval[e + 2], v3 = sval[e + 3];
    float4 h0 = h4[(long)c0 * 16 + li];
    float4 h1 = h4[(long)c1 * 16 + li];
    float4 h2 = h4[(long)c2 * 16 + li];
    float4 h3 = h4[(long)c3 * 16 + li];
    acc.x += v0 * h0.x + v1 * h1.x + v2 * h2.x + v3 * h3.x;
    acc.y += v0 * h0.y + v1 * h1.y + v2 * h2.y + v3 * h3.y;
    acc.z += v0 * h0.z + v1 * h1.z + v2 * h2.z + v3 * h3.z;
    acc.w += v0 * h0.w + v1 * h1.w + v2 * h2.w + v3 * h3.w;
  }
  for (; e < hi; ++e) {
    float v = sval[e];
    float4 hv = h4[(long)scol[e] * 16 + li];
    acc.x += v * hv.x;
    acc.y += v * hv.y;
    acc.z += v * hv.z;
    acc.w += v * hv.w;
  }
  float4* o = (float4*)(half ? outC : outS);
  o[(long)r * 16 + li] = acc;
}

// ---------------- fused dense chain ----------------
// H[n][64] = relu(Ax@W1 + b1) @ W2, Ax given as halves AxA/AxB (n*64 each).
// LDS: xs 16KB (Ax tile; relu'd in place, each wave touches ONLY its own
// 8 rows) + ws 16KB (W staged in 16KB chunks) = 32KB -> 5 blocks/CU.
__global__ __launch_bounds__(256) void fused_l1l2(
    const float* __restrict__ AxA, const float* __restrict__ AxB,
    const float* __restrict__ W1, const float* __restrict__ B1,
    const float* __restrict__ W2, float* __restrict__ H, int nrows) {
  __shared__ __attribute__((aligned(16))) float xs[32 * 128];
  __shared__ __attribute__((aligned(16))) float ws[32 * 128];
  int tid = threadIdx.x;
  long row0 = (long)blockIdx.x * 32;

  // stage Ax tile (coalesced) from the two halves
  const float4* A4 = (const float4*)AxA;
  const float4* B4 = (const float4*)AxB;
  float4* xs4 = (float4*)xs;
#pragma unroll
  for (int i = 0; i < 4; ++i) {
    int flat = i * 256 + tid;  // 32 rows x 32 float4
    int rl = flat >> 5, f4 = flat & 31;
    long rr = row0 + rl;
    float4 sv = make_float4(0.f, 0.f, 0.f, 0.f);
    if (rr < nrows)
      sv = (f4 < 16) ? A4[rr * 16 + f4] : B4[rr * 16 + (f4 - 16)];
    xs4[flat] = sv;
  }

  int c0 = tid & 63;
  int wv = tid >> 6;
  const float* xrow = xs + wv * 8 * 128;  // this wave's private 8 rows
  float acc0[8] = {}, acc1[8] = {};

  // ---- GEMM 1: s = Ax @ W1, W1 staged in 4 chunks of 32 k-rows (16KB) ----
  const float4* W14 = (const float4*)W1;
  float4* ws4 = (float4*)ws;
#pragma unroll
  for (int p = 0; p < 4; ++p) {
    if (p) __syncthreads();  // WAR: all waves done with previous chunk
#pragma unroll
    for (int i = 0; i < 4; ++i)
      ws4[i * 256 + tid] = W14[p * 1024 + i * 256 + tid];
    __syncthreads();  // RAW (p==0 also covers xs staging)
#pragma unroll
    for (int k4 = 0; k4 < 8; ++k4) {
      float wa[4], wb[4];
#pragma unroll
      for (int j = 0; j < 4; ++j) {
        wa[j] = ws[(k4 * 4 + j) * 128 + c0];
        wb[j] = ws[(k4 * 4 + j) * 128 + c0 + 64];
      }
#pragma unroll
      for (int r = 0; r < 8; ++r) {
        float4 xv = *(const float4*)(xrow + r * 128 + p * 32 + k4 * 4);
        acc0[r] += xv.x * wa[0] + xv.y * wa[1] + xv.z * wa[2] + xv.w * wa[3];
        acc1[r] += xv.x * wb[0] + xv.y * wb[1] + xv.z * wb[2] + xv.w * wb[3];
      }
    }
  }

  // ---- relu(s + b1) written back into xs (own rows only; no cross-wave
  // hazard since every wave reads/writes only its own 8 rows) ----
  float b1a = B1[c0], b1b = B1[c0 + 64];
#pragma unroll
  for (int r = 0; r < 8; ++r) {
    xs[(wv * 8 + r) * 128 + c0] = fmaxf(acc0[r] + b1a, 0.f);
    xs[(wv * 8 + r) * 128 + c0 + 64] = fmaxf(acc1[r] + b1b, 0.f);
  }

  // ---- GEMM 2: hw = h @ W2, W2 staged in 2 chunks of 64 k-rows (16KB) ----
  const float4* W24 = (const float4*)W2;
  float acc2[8] = {};
#pragma unroll
  for (int q = 0; q < 2; ++q) {
    __syncthreads();  // WAR on ws
#pragma unroll
    for (int i = 0; i < 4; ++i)
      ws4[i * 256 + tid] = W24[q * 1024 + i * 256 + tid];
    __syncthreads();
#pragma unroll
    for (int k4 = 0; k4 < 16; ++k4) {
      float wk[4];
#pragma unroll
      for (int j = 0; j < 4; ++j) wk[j] = ws[(k4 * 4 + j) * 64 + c0];
#pragma unroll
      for (int r = 0; r < 8; ++r) {
        float4 xv = *(const float4*)(xrow + r * 128 + q * 64 + k4 * 4);
        acc2[r] += xv.x * wk[0] + xv.y * wk[1] + xv.z * wk[2] + xv.w * wk[3];
      }
    }
  }
#pragma unroll
  for (int r = 0; r < 8; ++r) {
    long rr = row0 + wv * 8 + r;
    if (rr < nrows) H[rr * 64 + c0] = acc2[r];
  }
}

// ---------------- final fuse (16 lanes per node) ----------------
__global__ __launch_bounds__(256) void final_fuse(
    const float* __restrict__ emb1, const float* __restrict__ emb2,
    const float* __restrict__ com1, const float* __restrict__ com2,
    const float* __restrict__ attw1, const float* __restrict__ attb1,
    const float* __restrict__ attw2, const float* __restrict__ mlpw,
    const float* __restrict__ mlpb, float* __restrict__ out_logp,
    float* __restrict__ out_beta, float* __restrict__ out_emb, int n) {
  __shared__ __attribute__((aligned(16))) float w1t[16][64];
  __shared__ __attribute__((aligned(16))) float mwt[8][64];
  __shared__ float b1s[16];
  __shared__ float w2s[16];
  __shared__ float mbs[8];
  int tid = threadIdx.x;
  for (int idx = tid; idx < 1024; idx += 256)
    w1t[idx & 15][idx >> 4] = attw1[idx];
  for (int idx = tid; idx < 512; idx += 256)
    mwt[idx & 7][idx >> 3] = mlpw[idx];
  if (tid < 16) {
    b1s[tid] = attb1[tid];
    w2s[tid] = attw2[tid];
  }
  if (tid < 8) mbs[tid] = mlpb[tid];
  __syncthreads();

  int lane = tid & 15;
  long i = ((long)blockIdx.x * 256 + tid) >> 4;
  bool alive = i < n;
  long ii = alive ? i : (long)(n - 1);

  float4 z0 = ((const float4*)emb1)[ii * 16 + lane];
  float4 z1 = ((const float4*)emb2)[ii * 16 + lane];
  float4 x1 = ((const float4*)com1)[ii * 16 + lane];
  float4 x2 = ((const float4*)com2)[ii * 16 + lane];
  float4 z2 = make_float4(0.5f * (x1.x + x2.x), 0.5f * (x1.y + x2.y),
                          0.5f * (x1.z + x2.z), 0.5f * (x1.w + x2.w));

  float a0[16], a1[16], a2[16];
#pragma unroll
  for (int m = 0; m < 16; ++m) {
    float4 w = *(const float4*)&w1t[m][lane * 4];
    a0[m] = z0.x * w.x + z0.y * w.y + z0.z * w.z + z0.w * w.w;
    a1[m] = z1.x * w.x + z1.y * w.y + z1.z * w.z + z1.w * w.w;
    a2[m] = z2.x * w.x + z2.y * w.y + z2.z * w.z + z2.w * w.w;
  }
#pragma unroll
  for (int d = 1; d < 16; d <<= 1) {
#pragma unroll
    for (int m = 0; m < 16; ++m) {
      a0[m] += __shfl_xor(a0[m], d);
      a1[m] += __shfl_xor(a1[m], d);
      a2[m] += __shfl_xor(a2[m], d);
    }
  }
  float sc0 = 0.f, sc1 = 0.f, sc2 = 0.f;
#pragma unroll
  for (int m = 0; m < 16; ++m) {
    float wm = w2s[m], bm = b1s[m];
    sc0 += tanhf(a0[m] + bm) * wm;
    sc1 += tanhf(a1[m] + bm) * wm;
    sc2 += tanhf(a2[m] + bm) * wm;
  }
  float mx = fmaxf(sc0, fmaxf(sc1, sc2));
  float ex0 = expf(sc0 - mx), ex1 = expf(sc1 - mx), ex2 = expf(sc2 - mx);
  float inv = 1.f / (ex0 + ex1 + ex2);
  float be0 = ex0 * inv, be1 = ex1 * inv, be2 = ex2 * inv;

  float4 em;
  em.x = be0 * z0.x + be1 * z1.x + be2 * z2.x;
  em.y = be0 * z0.y + be1 * z1.y + be2 * z2.y;
  em.z = be0 * z0.z + be1 * z1.z + be2 * z2.z;
  em.w = be0 * z0.w + be1 * z1.w + be2 * z2.w;
  if (alive) ((float4*)out_emb)[i * 16 + lane] = em;

  float lg[8];
#pragma unroll
  for (int p = 0; p < 8; ++p) {
    float4 w = *(const float4*)&mwt[p][lane * 4];
    lg[p] = em.x * w.x + em.y * w.y + em.z * w.z + em.w * w.w;
  }
#pragma unroll
  for (int d = 1; d < 16; d <<= 1) {
#pragma unroll
    for (int p = 0; p < 8; ++p) lg[p] += __shfl_xor(lg[p], d);
  }
#pragma unroll
  for (int p = 0; p < 8; ++p) lg[p] += mbs[p];
  float m2 = lg[0];
#pragma unroll
  for (int p = 1; p < 8; ++p) m2 = fmaxf(m2, lg[p]);
  float ssum = 0.f;
#pragma unroll
  for (int p = 0; p < 8; ++p) ssum += expf(lg[p] - m2);
  float ls = m2 + logf(ssum);

  if (alive && lane == 0) {
    float4 o0 = make_float4(lg[0] - ls, lg[1] - ls, lg[2] - ls, lg[3] - ls);
    float4 o1 = make_float4(lg[4] - ls, lg[5] - ls, lg[6] - ls, lg[7] - ls);
    *(float4*)&out_logp[i * 8] = o0;
    *(float4*)&out_logp[i * 8 + 4] = o1;
    out_beta[i * 3 + 0] = be0;
    out_beta[i * 3 + 1] = be1;
    out_beta[i * 3 + 2] = be2;
  }
}

extern "C" void kernel_launch(void* const* d_in, const int* in_sizes, int n_in,
                              void* d_out, int out_size, void* d_ws,
                              size_t ws_size, hipStream_t stream) {
  const float* x = (const float*)d_in[0];
  const int* srow = (const int*)d_in[1];
  const int* scol_in = (const int*)d_in[2];
  const float* sval_in = (const float*)d_in[3];
  const int* frow = (const int*)d_in[4];
  const int* fcol_in = (const int*)d_in[5];
  const float* fval_in = (const float*)d_in[6];
  const float* w_s1_1 = (const float*)d_in[7];
  const float* b_s1_1 = (const float*)d_in[8];
  const float* w_s1_2 = (const float*)d_in[9];
  const float* b_s1_2 = (const float*)d_in[10];
  const float* w_s2_1 = (const float*)d_in[11];
  const float* b_s2_1 = (const float*)d_in[12];
  const float* w_s2_2 = (const float*)d_in[13];
  const float* b_s2_2 = (const float*)d_in[14];
  const float* w_c_1 = (const float*)d_in[15];
  const float* b_c_1 = (const float*)d_in[16];
  const float* w_c_2 = (const float*)d_in[17];
  const float* b_c_2 = (const float*)d_in[18];
  const float* attw1 = (const float*)d_in[19];
  const float* attb1 = (const float*)d_in[20];
  const float* attw2 = (const float*)d_in[21];
  const float* mlpw = (const float*)d_in[22];
  const float* mlpb = (const float*)d_in[23];

  const int n = in_sizes[0] / 128;  // 100000
  const int e = in_sizes[1];        // 1600000

  float* out = (float*)d_out;
  float* o_logp = out;
  float* o_beta = out + (size_t)n * 8;
  float* o_emb1 = out + (size_t)n * 11;
  float* o_com1 = o_emb1 + (size_t)n * 64;
  float* o_com2 = o_com1 + (size_t)n * 64;
  float* o_emb2 = o_com2 + (size_t)n * 64;
  float* o_emb = o_emb2 + (size_t)n * 64;

  // workspace layout (~91MB, within proven budget)
  float* axA = (float*)d_ws;                      // n*64 (Ax feats 0..63)
  float* axB = axA + (size_t)n * 64;              // n*64 (Ax feats 64..127)
  float* hwC = axB + (size_t)n * 64;              // n*64 (C-chain hw)
  int* cnt = (int*)(hwC + (size_t)n * 64);        // n
  int* rowptr = cnt + n;                          // n+1
  int* woff = rowptr + n + 1;                     // n
  int* part = woff + n;                           // <=256
  int* g_col = part + 256;                        // e
  float* g_val = (float*)(g_col + e);             // e

  float* hwS = o_emb;  // scratch; final_fuse overwrites at the very end

  const int gemmBlocks = (n + 31) / 32;
  const int histBlocks = (e + 255) / 256;
  const int scanBlocks = (n + 1023) / 1024;
  const int spmmBlocks = (n + 7) / 8;

  auto build_csr = [&](const int* r, const int* c, const float* v) {
    hipMemsetAsync(cnt, 0, (size_t)n * sizeof(int), stream);
    hist_kernel<<<histBlocks, 256, 0, stream>>>(r, cnt, e);
    scan_partial<<<scanBlocks, 256, 0, stream>>>(cnt, part, n);
    scan_tops<<<1, 256, 0, stream>>>(part, scanBlocks);
    scan_final<<<scanBlocks, 256, 0, stream>>>(cnt, part, rowptr, woff, n, e);
    scatter_kernel<<<histBlocks, 256, 0, stream>>>(r, c, v, woff, g_col,
                                                   g_val, e);
  };

  // --- graph sadj: emb1 (w_s1) + com1 (w_c) ---
  build_csr(srow, scol_in, sval_in);
  spmm_csr_128<<<spmmBlocks, 256, 0, stream>>>(rowptr, g_col, g_val, x, axA,
                                               axB, n);
  fused_l1l2<<<gemmBlocks, 256, 0, stream>>>(axA, axB, w_s1_1, b_s1_1, w_s1_2,
                                             hwS, n);
  fused_l1l2<<<gemmBlocks, 256, 0, stream>>>(axA, axB, w_c_1, b_c_1, w_c_2,
                                             hwC, n);
  spmm_dual64<<<spmmBlocks, 256, 0, stream>>>(rowptr, g_col, g_val, hwS, hwC,
                                              b_s1_2, b_c_2, o_emb1, o_com1,
                                              n);

  // --- graph fadj: com2 (w_c) + emb2 (w_s2) ---
  build_csr(frow, fcol_in, fval_in);
  spmm_csr_128<<<spmmBlocks, 256, 0, stream>>>(rowptr, g_col, g_val, x, axA,
                                               axB, n);
  fused_l1l2<<<gemmBlocks, 256, 0, stream>>>(axA, axB, w_s2_1, b_s2_1, w_s2_2,
                                             hwS, n);
  fused_l1l2<<<gemmBlocks, 256, 0, stream>>>(axA, axB, w_c_1, b_c_1, w_c_2,
                                             hwC, n);
  spmm_dual64<<<spmmBlocks, 256, 0, stream>>>(rowptr, g_col, g_val, hwS, hwC,
                                              b_s2_2, b_c_2, o_emb2, o_com2,
                                              n);

  final_fuse<<<(int)(((long)n * 16 + 255) / 256), 256, 0, stream>>>(
      o_emb1, o_emb2, o_com1, o_com2, attw1, attb1, attw2, mlpw, mlpb, o_logp,
      o_beta, o_emb, n);
}

// Round 8
// 1417.843 us; speedup vs baseline: 3.3532x; 3.3532x over previous
//
#include <hip/hip_runtime.h>

// ---------------------------------------------------------------------------
// SFGCN forward on MI355X, round 8:
//  - REVERT fused_l1l2 to round-6 structure (48KB LDS, 2-phase W1, 68 VGPR).
//    Round-7's 6-chunk fully-unrolled staging caused register spills
//    (VGPR 256, 1.85GB scratch writes, 7x slowdown).
//  - KEEP spmm_dual64 (both 64-feat SpMMs in one launch) and edge-unroll x4
//    in spmm_csr_128 (both correctness-proven in round 7).
// ---------------------------------------------------------------------------

// ---------------- CSR build ----------------

__global__ __launch_bounds__(256) void hist_kernel(
    const int* __restrict__ row, int* __restrict__ cnt, int e) {
  int i = blockIdx.x * 256 + threadIdx.x;
  if (i < e) atomicAdd(&cnt[row[i]], 1);
}

__global__ __launch_bounds__(256) void scan_partial(
    const int* __restrict__ cnt, int* __restrict__ part, int n) {
  __shared__ int red[256];
  int t = threadIdx.x;
  int base = blockIdx.x * 1024 + t * 4;
  int s = 0;
#pragma unroll
  for (int j = 0; j < 4; ++j) {
    int idx = base + j;
    if (idx < n) s += cnt[idx];
  }
  red[t] = s;
  __syncthreads();
#pragma unroll
  for (int d = 128; d > 0; d >>= 1) {
    if (t < d) red[t] += red[t + d];
    __syncthreads();
  }
  if (t == 0) part[blockIdx.x] = red[0];
}

__global__ __launch_bounds__(256) void scan_tops(int* __restrict__ part,
                                                 int nb) {
  __shared__ int lds[256];
  int t = threadIdx.x;
  lds[t] = (t < nb) ? part[t] : 0;
  __syncthreads();
#pragma unroll
  for (int d = 1; d < 256; d <<= 1) {
    int v = (t >= d) ? lds[t - d] : 0;
    __syncthreads();
    lds[t] += v;
    __syncthreads();
  }
  if (t < nb) part[t] = (t == 0) ? 0 : lds[t - 1];
}

__global__ __launch_bounds__(256) void scan_final(
    const int* __restrict__ cnt, const int* __restrict__ part,
    int* __restrict__ rowptr, int* __restrict__ woff, int n, int e) {
  __shared__ int lds[256];
  int t = threadIdx.x;
  int base = blockIdx.x * 1024 + t * 4;
  int c[4];
  int s = 0;
#pragma unroll
  for (int j = 0; j < 4; ++j) {
    int idx = base + j;
    c[j] = (idx < n) ? cnt[idx] : 0;
    s += c[j];
  }
  lds[t] = s;
  __syncthreads();
#pragma unroll
  for (int d = 1; d < 256; d <<= 1) {
    int v = (t >= d) ? lds[t - d] : 0;
    __syncthreads();
    lds[t] += v;
    __syncthreads();
  }
  int off = part[blockIdx.x] + ((t == 0) ? 0 : lds[t - 1]);
#pragma unroll
  for (int j = 0; j < 4; ++j) {
    int idx = base + j;
    if (idx < n) {
      rowptr[idx] = off;
      woff[idx] = off;
      off += c[j];
    }
  }
  if (blockIdx.x == 0 && t == 0) rowptr[n] = e;
}

__global__ __launch_bounds__(256) void scatter_kernel(
    const int* __restrict__ row, const int* __restrict__ col,
    const float* __restrict__ val, int* __restrict__ woff,
    int* __restrict__ scol, float* __restrict__ sval, int e) {
  int i = blockIdx.x * 256 + threadIdx.x;
  if (i >= e) return;
  int r = row[i];
  int p = atomicAdd(&woff[r], 1);
  scol[p] = col[i];
  sval[p] = val[i];
}

// ---------------- CSR SpMM ----------------

// 128 feats: 32 lanes/row, edge-unroll x4; output split into halves OA/OB.
__global__ __launch_bounds__(256) void spmm_csr_128(
    const int* __restrict__ rowptr, const int* __restrict__ scol,
    const float* __restrict__ sval, const float* __restrict__ h,
    float* __restrict__ OA, float* __restrict__ OB, int n) {
  int tid = threadIdx.x;
  int r = blockIdx.x * 8 + (tid >> 5);
  if (r >= n) return;
  int lane = tid & 31;
  int lo = rowptr[r], hi = rowptr[r + 1];
  const float4* h4 = (const float4*)h;
  float4 acc = make_float4(0.f, 0.f, 0.f, 0.f);
  int e = lo;
  for (; e + 4 <= hi; e += 4) {
    int c0 = scol[e], c1 = scol[e + 1], c2 = scol[e + 2], c3 = scol[e + 3];
    float v0 = sval[e], v1 = sval[e + 1], v2 = sval[e + 2], v3 = sval[e + 3];
    float4 h0 = h4[(long)c0 * 32 + lane];
    float4 h1 = h4[(long)c1 * 32 + lane];
    float4 h2 = h4[(long)c2 * 32 + lane];
    float4 h3 = h4[(long)c3 * 32 + lane];
    acc.x += v0 * h0.x + v1 * h1.x + v2 * h2.x + v3 * h3.x;
    acc.y += v0 * h0.y + v1 * h1.y + v2 * h2.y + v3 * h3.y;
    acc.z += v0 * h0.z + v1 * h1.z + v2 * h2.z + v3 * h3.z;
    acc.w += v0 * h0.w + v1 * h1.w + v2 * h2.w + v3 * h3.w;
  }
  for (; e < hi; ++e) {
    float v = sval[e];
    float4 hv = h4[(long)scol[e] * 32 + lane];
    acc.x += v * hv.x;
    acc.y += v * hv.y;
    acc.z += v * hv.z;
    acc.w += v * hv.w;
  }
  if (lane < 16)
    ((float4*)OA)[(long)r * 16 + lane] = acc;
  else
    ((float4*)OB)[(long)r * 16 + (lane - 16)] = acc;
}

// Dual 64-feat SpMM: 32 lanes/row; lanes 0-15 gather hS -> outS (+bS),
// lanes 16-31 gather hC -> outC (+bC). Edge metadata read once.
__global__ __launch_bounds__(256) void spmm_dual64(
    const int* __restrict__ rowptr, const int* __restrict__ scol,
    const float* __restrict__ sval, const float* __restrict__ hS,
    const float* __restrict__ hC, const float* __restrict__ bS,
    const float* __restrict__ bC, float* __restrict__ outS,
    float* __restrict__ outC, int n) {
  int tid = threadIdx.x;
  int r = blockIdx.x * 8 + (tid >> 5);
  if (r >= n) return;
  int lane = tid & 31;
  int half = lane >> 4;
  int li = lane & 15;
  const float4* h4 = (const float4*)(half ? hC : hS);
  float4 acc = ((const float4*)(half ? bC : bS))[li];
  int lo = rowptr[r], hi = rowptr[r + 1];
  int e = lo;
  for (; e + 4 <= hi; e += 4) {
    int c0 = scol[e], c1 = scol[e + 1], c2 = scol[e + 2], c3 = scol[e + 3];
    float v0 = sval[e], v1 = sval[e + 1], v2 = sval[e + 2], v3 = sval[e + 3];
    float4 h0 = h4[(long)c0 * 16 + li];
    float4 h1 = h4[(long)c1 * 16 + li];
    float4 h2 = h4[(long)c2 * 16 + li];
    float4 h3 = h4[(long)c3 * 16 + li];
    acc.x += v0 * h0.x + v1 * h1.x + v2 * h2.x + v3 * h3.x;
    acc.y += v0 * h0.y + v1 * h1.y + v2 * h2.y + v3 * h3.y;
    acc.z += v0 * h0.z + v1 * h1.z + v2 * h2.z + v3 * h3.z;
    acc.w += v0 * h0.w + v1 * h1.w + v2 * h2.w + v3 * h3.w;
  }
  for (; e < hi; ++e) {
    float v = sval[e];
    float4 hv = h4[(long)scol[e] * 16 + li];
    acc.x += v * hv.x;
    acc.y += v * hv.y;
    acc.z += v * hv.z;
    acc.w += v * hv.w;
  }
  float4* o = (float4*)(half ? outC : outS);
  o[(long)r * 16 + li] = acc;
}

// ---------------- fused dense chain (round-6 structure, known-good) -------
// H[n][64] = relu(Ax@W1 + b1) @ W2, Ax given as halves AxA/AxB (n*64 each).
// LDS: xs 16KB (Ax tile; reused for relu'd s) + ws 32KB (W1 k-half / W2).
// 48KB -> 3 blocks/CU. 68 VGPR, no spills.
__global__ __launch_bounds__(256) void fused_l1l2(
    const float* __restrict__ AxA, const float* __restrict__ AxB,
    const float* __restrict__ W1, const float* __restrict__ B1,
    const float* __restrict__ W2, float* __restrict__ H, int nrows) {
  __shared__ __attribute__((aligned(16))) float xs[32 * 128];
  __shared__ __attribute__((aligned(16))) float ws[64 * 128];
  int tid = threadIdx.x;
  long row0 = (long)blockIdx.x * 32;

  // stage Ax tile (coalesced) from the two halves
  const float4* A4 = (const float4*)AxA;
  const float4* B4 = (const float4*)AxB;
  float4* xs4 = (float4*)xs;
#pragma unroll
  for (int i = 0; i < 4; ++i) {
    int flat = i * 256 + tid;  // 32 rows x 32 float4
    int rl = flat >> 5, f4 = flat & 31;
    long rr = row0 + rl;
    float4 sv = make_float4(0.f, 0.f, 0.f, 0.f);
    if (rr < nrows)
      sv = (f4 < 16) ? A4[rr * 16 + f4] : B4[rr * 16 + (f4 - 16)];
    xs4[flat] = sv;
  }

  int c0 = tid & 63;
  int wv = tid >> 6;
  const float* xrow = xs + wv * 8 * 128;  // this wave's private 8 rows
  float acc0[8] = {}, acc1[8] = {};

  // ---- GEMM 1: s = Ax @ W1 (k split in two 64-row phases of W1) ----
  const float4* W14 = (const float4*)W1;
  float4* ws4 = (float4*)ws;
#pragma unroll
  for (int ph = 0; ph < 2; ++ph) {
    if (ph) __syncthreads();  // WAR on ws
#pragma unroll
    for (int i = 0; i < 8; ++i)
      ws4[i * 256 + tid] = W14[ph * 2048 + i * 256 + tid];
    __syncthreads();  // ph==0 also covers xs staging
#pragma unroll 4
    for (int k4 = 0; k4 < 16; ++k4) {
      float wa[4], wb[4];
#pragma unroll
      for (int j = 0; j < 4; ++j) {
        wa[j] = ws[(k4 * 4 + j) * 128 + c0];
        wb[j] = ws[(k4 * 4 + j) * 128 + c0 + 64];
      }
#pragma unroll
      for (int r = 0; r < 8; ++r) {
        float4 xv = *(const float4*)(xrow + r * 128 + ph * 64 + k4 * 4);
        acc0[r] += xv.x * wa[0] + xv.y * wa[1] + xv.z * wa[2] + xv.w * wa[3];
        acc1[r] += xv.x * wb[0] + xv.y * wb[1] + xv.z * wb[2] + xv.w * wb[3];
      }
    }
  }

  // ---- relu(s + b1) written back into xs (own rows only) ----
  float b1a = B1[c0], b1b = B1[c0 + 64];
  __syncthreads();  // all waves done reading ws / xs phase data
#pragma unroll
  for (int r = 0; r < 8; ++r) {
    xs[(wv * 8 + r) * 128 + c0] = fmaxf(acc0[r] + b1a, 0.f);
    xs[(wv * 8 + r) * 128 + c0 + 64] = fmaxf(acc1[r] + b1b, 0.f);
  }

  // ---- stage W2 (128x64 = 32KB) into ws ----
  const float4* W24 = (const float4*)W2;
#pragma unroll
  for (int i = 0; i < 8; ++i) ws4[i * 256 + tid] = W24[i * 256 + tid];
  __syncthreads();

  // ---- GEMM 2: hw = h @ W2 ----
  float acc2[8] = {};
#pragma unroll 4
  for (int k4 = 0; k4 < 32; ++k4) {
    float wk[4];
#pragma unroll
    for (int j = 0; j < 4; ++j) wk[j] = ws[(k4 * 4 + j) * 64 + c0];
#pragma unroll
    for (int r = 0; r < 8; ++r) {
      float4 xv = *(const float4*)(xrow + r * 128 + k4 * 4);
      acc2[r] += xv.x * wk[0] + xv.y * wk[1] + xv.z * wk[2] + xv.w * wk[3];
    }
  }
#pragma unroll
  for (int r = 0; r < 8; ++r) {
    long rr = row0 + wv * 8 + r;
    if (rr < nrows) H[rr * 64 + c0] = acc2[r];
  }
}

// ---------------- final fuse (16 lanes per node) ----------------
__global__ __launch_bounds__(256) void final_fuse(
    const float* __restrict__ emb1, const float* __restrict__ emb2,
    const float* __restrict__ com1, const float* __restrict__ com2,
    const float* __restrict__ attw1, const float* __restrict__ attb1,
    const float* __restrict__ attw2, const float* __restrict__ mlpw,
    const float* __restrict__ mlpb, float* __restrict__ out_logp,
    float* __restrict__ out_beta, float* __restrict__ out_emb, int n) {
  __shared__ __attribute__((aligned(16))) float w1t[16][64];
  __shared__ __attribute__((aligned(16))) float mwt[8][64];
  __shared__ float b1s[16];
  __shared__ float w2s[16];
  __shared__ float mbs[8];
  int tid = threadIdx.x;
  for (int idx = tid; idx < 1024; idx += 256)
    w1t[idx & 15][idx >> 4] = attw1[idx];
  for (int idx = tid; idx < 512; idx += 256)
    mwt[idx & 7][idx >> 3] = mlpw[idx];
  if (tid < 16) {
    b1s[tid] = attb1[tid];
    w2s[tid] = attw2[tid];
  }
  if (tid < 8) mbs[tid] = mlpb[tid];
  __syncthreads();

  int lane = tid & 15;
  long i = ((long)blockIdx.x * 256 + tid) >> 4;
  bool alive = i < n;
  long ii = alive ? i : (long)(n - 1);

  float4 z0 = ((const float4*)emb1)[ii * 16 + lane];
  float4 z1 = ((const float4*)emb2)[ii * 16 + lane];
  float4 x1 = ((const float4*)com1)[ii * 16 + lane];
  float4 x2 = ((const float4*)com2)[ii * 16 + lane];
  float4 z2 = make_float4(0.5f * (x1.x + x2.x), 0.5f * (x1.y + x2.y),
                          0.5f * (x1.z + x2.z), 0.5f * (x1.w + x2.w));

  float a0[16], a1[16], a2[16];
#pragma unroll
  for (int m = 0; m < 16; ++m) {
    float4 w = *(const float4*)&w1t[m][lane * 4];
    a0[m] = z0.x * w.x + z0.y * w.y + z0.z * w.z + z0.w * w.w;
    a1[m] = z1.x * w.x + z1.y * w.y + z1.z * w.z + z1.w * w.w;
    a2[m] = z2.x * w.x + z2.y * w.y + z2.z * w.z + z2.w * w.w;
  }
#pragma unroll
  for (int d = 1; d < 16; d <<= 1) {
#pragma unroll
    for (int m = 0; m < 16; ++m) {
      a0[m] += __shfl_xor(a0[m], d);
      a1[m] += __shfl_xor(a1[m], d);
      a2[m] += __shfl_xor(a2[m], d);
    }
  }
  float sc0 = 0.f, sc1 = 0.f, sc2 = 0.f;
#pragma unroll
  for (int m = 0; m < 16; ++m) {
    float wm = w2s[m], bm = b1s[m];
    sc0 += tanhf(a0[m] + bm) * wm;
    sc1 += tanhf(a1[m] + bm) * wm;
    sc2 += tanhf(a2[m] + bm) * wm;
  }
  float mx = fmaxf(sc0, fmaxf(sc1, sc2));
  float ex0 = expf(sc0 - mx), ex1 = expf(sc1 - mx), ex2 = expf(sc2 - mx);
  float inv = 1.f / (ex0 + ex1 + ex2);
  float be0 = ex0 * inv, be1 = ex1 * inv, be2 = ex2 * inv;

  float4 em;
  em.x = be0 * z0.x + be1 * z1.x + be2 * z2.x;
  em.y = be0 * z0.y + be1 * z1.y + be2 * z2.y;
  em.z = be0 * z0.z + be1 * z1.z + be2 * z2.z;
  em.w = be0 * z0.w + be1 * z1.w + be2 * z2.w;
  if (alive) ((float4*)out_emb)[i * 16 + lane] = em;

  float lg[8];
#pragma unroll
  for (int p = 0; p < 8; ++p) {
    float4 w = *(const float4*)&mwt[p][lane * 4];
    lg[p] = em.x * w.x + em.y * w.y + em.z * w.z + em.w * w.w;
  }
#pragma unroll
  for (int d = 1; d < 16; d <<= 1) {
#pragma unroll
    for (int p = 0; p < 8; ++p) lg[p] += __shfl_xor(lg[p], d);
  }
#pragma unroll
  for (int p = 0; p < 8; ++p) lg[p] += mbs[p];
  float m2 = lg[0];
#pragma unroll
  for (int p = 1; p < 8; ++p) m2 = fmaxf(m2, lg[p]);
  float ssum = 0.f;
#pragma unroll
  for (int p = 0; p < 8; ++p) ssum += expf(lg[p] - m2);
  float ls = m2 + logf(ssum);

  if (alive && lane == 0) {
    float4 o0 = make_float4(lg[0] - ls, lg[1] - ls, lg[2] - ls, lg[3] - ls);
    float4 o1 = make_float4(lg[4] - ls, lg[5] - ls, lg[6] - ls, lg[7] - ls);
    *(float4*)&out_logp[i * 8] = o0;
    *(float4*)&out_logp[i * 8 + 4] = o1;
    out_beta[i * 3 + 0] = be0;
    out_beta[i * 3 + 1] = be1;
    out_beta[i * 3 + 2] = be2;
  }
}

extern "C" void kernel_launch(void* const* d_in, const int* in_sizes, int n_in,
                              void* d_out, int out_size, void* d_ws,
                              size_t ws_size, hipStream_t stream) {
  const float* x = (const float*)d_in[0];
  const int* srow = (const int*)d_in[1];
  const int* scol_in = (const int*)d_in[2];
  const float* sval_in = (const float*)d_in[3];
  const int* frow = (const int*)d_in[4];
  const int* fcol_in = (const int*)d_in[5];
  const float* fval_in = (const float*)d_in[6];
  const float* w_s1_1 = (const float*)d_in[7];
  const float* b_s1_1 = (const float*)d_in[8];
  const float* w_s1_2 = (const float*)d_in[9];
  const float* b_s1_2 = (const float*)d_in[10];
  const float* w_s2_1 = (const float*)d_in[11];
  const float* b_s2_1 = (const float*)d_in[12];
  const float* w_s2_2 = (const float*)d_in[13];
  const float* b_s2_2 = (const float*)d_in[14];
  const float* w_c_1 = (const float*)d_in[15];
  const float* b_c_1 = (const float*)d_in[16];
  const float* w_c_2 = (const float*)d_in[17];
  const float* b_c_2 = (const float*)d_in[18];
  const float* attw1 = (const float*)d_in[19];
  const float* attb1 = (const float*)d_in[20];
  const float* attw2 = (const float*)d_in[21];
  const float* mlpw = (const float*)d_in[22];
  const float* mlpb = (const float*)d_in[23];

  const int n = in_sizes[0] / 128;  // 100000
  const int e = in_sizes[1];        // 1600000

  float* out = (float*)d_out;
  float* o_logp = out;
  float* o_beta = out + (size_t)n * 8;
  float* o_emb1 = out + (size_t)n * 11;
  float* o_com1 = o_emb1 + (size_t)n * 64;
  float* o_com2 = o_com1 + (size_t)n * 64;
  float* o_emb2 = o_com2 + (size_t)n * 64;
  float* o_emb = o_emb2 + (size_t)n * 64;

  // workspace layout (~91MB, within proven budget)
  float* axA = (float*)d_ws;                      // n*64 (Ax feats 0..63)
  float* axB = axA + (size_t)n * 64;              // n*64 (Ax feats 64..127)
  float* hwC = axB + (size_t)n * 64;              // n*64 (C-chain hw)
  int* cnt = (int*)(hwC + (size_t)n * 64);        // n
  int* rowptr = cnt + n;                          // n+1
  int* woff = rowptr + n + 1;                     // n
  int* part = woff + n;                           // <=256
  int* g_col = part + 256;                        // e
  float* g_val = (float*)(g_col + e);             // e

  float* hwS = o_emb;  // scratch; final_fuse overwrites at the very end

  const int gemmBlocks = (n + 31) / 32;
  const int histBlocks = (e + 255) / 256;
  const int scanBlocks = (n + 1023) / 1024;
  const int spmmBlocks = (n + 7) / 8;

  auto build_csr = [&](const int* r, const int* c, const float* v) {
    hipMemsetAsync(cnt, 0, (size_t)n * sizeof(int), stream);
    hist_kernel<<<histBlocks, 256, 0, stream>>>(r, cnt, e);
    scan_partial<<<scanBlocks, 256, 0, stream>>>(cnt, part, n);
    scan_tops<<<1, 256, 0, stream>>>(part, scanBlocks);
    scan_final<<<scanBlocks, 256, 0, stream>>>(cnt, part, rowptr, woff, n, e);
    scatter_kernel<<<histBlocks, 256, 0, stream>>>(r, c, v, woff, g_col,
                                                   g_val, e);
  };

  // --- graph sadj: emb1 (w_s1) + com1 (w_c) ---
  build_csr(srow, scol_in, sval_in);
  spmm_csr_128<<<spmmBlocks, 256, 0, stream>>>(rowptr, g_col, g_val, x, axA,
                                               axB, n);
  fused_l1l2<<<gemmBlocks, 256, 0, stream>>>(axA, axB, w_s1_1, b_s1_1, w_s1_2,
                                             hwS, n);
  fused_l1l2<<<gemmBlocks, 256, 0, stream>>>(axA, axB, w_c_1, b_c_1, w_c_2,
                                             hwC, n);
  spmm_dual64<<<spmmBlocks, 256, 0, stream>>>(rowptr, g_col, g_val, hwS, hwC,
                                              b_s1_2, b_c_2, o_emb1, o_com1,
                                              n);

  // --- graph fadj: com2 (w_c) + emb2 (w_s2) ---
  build_csr(frow, fcol_in, fval_in);
  spmm_csr_128<<<spmmBlocks, 256, 0, stream>>>(rowptr, g_col, g_val, x, axA,
                                               axB, n);
  fused_l1l2<<<gemmBlocks, 256, 0, stream>>>(axA, axB, w_s2_1, b_s2_1, w_s2_2,
                                             hwS, n);
  fused_l1l2<<<gemmBlocks, 256, 0, stream>>>(axA, axB, w_c_1, b_c_1, w_c_2,
                                             hwC, n);
  spmm_dual64<<<spmmBlocks, 256, 0, stream>>>(rowptr, g_col, g_val, hwS, hwC,
                                              b_s2_2, b_c_2, o_emb2, o_com2,
                                              n);

  final_fuse<<<(int)(((long)n * 16 + 255) / 256), 256, 0, stream>>>(
      o_emb1, o_emb2, o_com1, o_com2, attw1, attb1, attw2, mlpw, mlpb, o_logp,
      o_beta, o_emb, n);
}

// Round 9
// 1223.131 us; speedup vs baseline: 3.8870x; 1.1592x over previous
//
#include <hip/hip_runtime.h>

// ---------------------------------------------------------------------------
// SFGCN forward on MI355X, round 9:
//  - bf16 GATHER SOURCES for all SpMMs (fp32 accumulate). x -> x_bf16 (25.6MB,
//    ~L2-resident), hw written as bf16 by fused_l1l2 epilogue. Halves the
//    random-gather HBM traffic that dominates spmm_csr_128/spmm_dual64.
//  - fused_l1l2 inner loops UNTOUCHED (round-7 spill lesson); only the final
//    store casts to bf16.
//  - x_bf16 lives in the o_emb output region (overwritten by final_fuse at
//    the very end); hwS/hwC moved into d_ws (total ~90.8MB, proven budget).
// ---------------------------------------------------------------------------

typedef unsigned short ushort_t;

__device__ __forceinline__ ushort_t f2bf(float f) {  // round-to-nearest-even
  unsigned u = __float_as_uint(f);
  unsigned r = (u + 0x7FFFu + ((u >> 16) & 1u)) >> 16;
  return (ushort_t)r;
}
__device__ __forceinline__ float bf2f(ushort_t b) {
  return __uint_as_float((unsigned)b << 16);
}

// total4 float4 chunks -> ushort4 bf16 chunks
__global__ __launch_bounds__(256) void cvt_bf16(
    const float* __restrict__ in, ushort_t* __restrict__ out, long total4) {
  long i = (long)blockIdx.x * 256 + threadIdx.x;
  if (i >= total4) return;
  float4 v = ((const float4*)in)[i];
  ushort4 o;
  o.x = f2bf(v.x);
  o.y = f2bf(v.y);
  o.z = f2bf(v.z);
  o.w = f2bf(v.w);
  ((ushort4*)out)[i] = o;
}

// ---------------- CSR build ----------------

__global__ __launch_bounds__(256) void hist_kernel(
    const int* __restrict__ row, int* __restrict__ cnt, int e) {
  int i = blockIdx.x * 256 + threadIdx.x;
  if (i < e) atomicAdd(&cnt[row[i]], 1);
}

__global__ __launch_bounds__(256) void scan_partial(
    const int* __restrict__ cnt, int* __restrict__ part, int n) {
  __shared__ int red[256];
  int t = threadIdx.x;
  int base = blockIdx.x * 1024 + t * 4;
  int s = 0;
#pragma unroll
  for (int j = 0; j < 4; ++j) {
    int idx = base + j;
    if (idx < n) s += cnt[idx];
  }
  red[t] = s;
  __syncthreads();
#pragma unroll
  for (int d = 128; d > 0; d >>= 1) {
    if (t < d) red[t] += red[t + d];
    __syncthreads();
  }
  if (t == 0) part[blockIdx.x] = red[0];
}

__global__ __launch_bounds__(256) void scan_tops(int* __restrict__ part,
                                                 int nb) {
  __shared__ int lds[256];
  int t = threadIdx.x;
  lds[t] = (t < nb) ? part[t] : 0;
  __syncthreads();
#pragma unroll
  for (int d = 1; d < 256; d <<= 1) {
    int v = (t >= d) ? lds[t - d] : 0;
    __syncthreads();
    lds[t] += v;
    __syncthreads();
  }
  if (t < nb) part[t] = (t == 0) ? 0 : lds[t - 1];
}

__global__ __launch_bounds__(256) void scan_final(
    const int* __restrict__ cnt, const int* __restrict__ part,
    int* __restrict__ rowptr, int* __restrict__ woff, int n, int e) {
  __shared__ int lds[256];
  int t = threadIdx.x;
  int base = blockIdx.x * 1024 + t * 4;
  int c[4];
  int s = 0;
#pragma unroll
  for (int j = 0; j < 4; ++j) {
    int idx = base + j;
    c[j] = (idx < n) ? cnt[idx] : 0;
    s += c[j];
  }
  lds[t] = s;
  __syncthreads();
#pragma unroll
  for (int d = 1; d < 256; d <<= 1) {
    int v = (t >= d) ? lds[t - d] : 0;
    __syncthreads();
    lds[t] += v;
    __syncthreads();
  }
  int off = part[blockIdx.x] + ((t == 0) ? 0 : lds[t - 1]);
#pragma unroll
  for (int j = 0; j < 4; ++j) {
    int idx = base + j;
    if (idx < n) {
      rowptr[idx] = off;
      woff[idx] = off;
      off += c[j];
    }
  }
  if (blockIdx.x == 0 && t == 0) rowptr[n] = e;
}

__global__ __launch_bounds__(256) void scatter_kernel(
    const int* __restrict__ row, const int* __restrict__ col,
    const float* __restrict__ val, int* __restrict__ woff,
    int* __restrict__ scol, float* __restrict__ sval, int e) {
  int i = blockIdx.x * 256 + threadIdx.x;
  if (i >= e) return;
  int r = row[i];
  int p = atomicAdd(&woff[r], 1);
  scol[p] = col[i];
  sval[p] = val[i];
}

// ---------------- CSR SpMM (bf16 gather, fp32 accumulate) ----------------

// 128 feats: 32 lanes/row, 4 bf16 feats/lane (8B loads), edge-unroll x4.
__global__ __launch_bounds__(256) void spmm_csr_128(
    const int* __restrict__ rowptr, const int* __restrict__ scol,
    const float* __restrict__ sval, const ushort_t* __restrict__ h,
    float* __restrict__ OA, float* __restrict__ OB, int n) {
  int tid = threadIdx.x;
  int r = blockIdx.x * 8 + (tid >> 5);
  if (r >= n) return;
  int lane = tid & 31;
  int lo = rowptr[r], hi = rowptr[r + 1];
  const ushort4* h4 = (const ushort4*)h;  // row stride = 32 ushort4
  float4 acc = make_float4(0.f, 0.f, 0.f, 0.f);
  int e = lo;
  for (; e + 4 <= hi; e += 4) {
    int c0 = scol[e], c1 = scol[e + 1], c2 = scol[e + 2], c3 = scol[e + 3];
    float v0 = sval[e], v1 = sval[e + 1], v2 = sval[e + 2], v3 = sval[e + 3];
    ushort4 q0 = h4[(long)c0 * 32 + lane];
    ushort4 q1 = h4[(long)c1 * 32 + lane];
    ushort4 q2 = h4[(long)c2 * 32 + lane];
    ushort4 q3 = h4[(long)c3 * 32 + lane];
    acc.x += v0 * bf2f(q0.x) + v1 * bf2f(q1.x) + v2 * bf2f(q2.x) + v3 * bf2f(q3.x);
    acc.y += v0 * bf2f(q0.y) + v1 * bf2f(q1.y) + v2 * bf2f(q2.y) + v3 * bf2f(q3.y);
    acc.z += v0 * bf2f(q0.z) + v1 * bf2f(q1.z) + v2 * bf2f(q2.z) + v3 * bf2f(q3.z);
    acc.w += v0 * bf2f(q0.w) + v1 * bf2f(q1.w) + v2 * bf2f(q2.w) + v3 * bf2f(q3.w);
  }
  for (; e < hi; ++e) {
    float v = sval[e];
    ushort4 q = h4[(long)scol[e] * 32 + lane];
    acc.x += v * bf2f(q.x);
    acc.y += v * bf2f(q.y);
    acc.z += v * bf2f(q.z);
    acc.w += v * bf2f(q.w);
  }
  if (lane < 16)
    ((float4*)OA)[(long)r * 16 + lane] = acc;
  else
    ((float4*)OB)[(long)r * 16 + (lane - 16)] = acc;
}

// Dual 64-feat SpMM, bf16 gather: lanes 0-15 -> hS/outS(+bS), 16-31 -> hC.
__global__ __launch_bounds__(256) void spmm_dual64(
    const int* __restrict__ rowptr, const int* __restrict__ scol,
    const float* __restrict__ sval, const ushort_t* __restrict__ hS,
    const ushort_t* __restrict__ hC, const float* __restrict__ bS,
    const float* __restrict__ bC, float* __restrict__ outS,
    float* __restrict__ outC, int n) {
  int tid = threadIdx.x;
  int r = blockIdx.x * 8 + (tid >> 5);
  if (r >= n) return;
  int lane = tid & 31;
  int half = lane >> 4;
  int li = lane & 15;
  const ushort4* h4 = (const ushort4*)(half ? hC : hS);  // row = 16 ushort4
  float4 acc = ((const float4*)(half ? bC : bS))[li];
  int lo = rowptr[r], hi = rowptr[r + 1];
  int e = lo;
  for (; e + 4 <= hi; e += 4) {
    int c0 = scol[e], c1 = scol[e + 1], c2 = scol[e + 2], c3 = scol[e + 3];
    float v0 = sval[e], v1 = sval[e + 1], v2 = sval[e + 2], v3 = sval[e + 3];
    ushort4 q0 = h4[(long)c0 * 16 + li];
    ushort4 q1 = h4[(long)c1 * 16 + li];
    ushort4 q2 = h4[(long)c2 * 16 + li];
    ushort4 q3 = h4[(long)c3 * 16 + li];
    acc.x += v0 * bf2f(q0.x) + v1 * bf2f(q1.x) + v2 * bf2f(q2.x) + v3 * bf2f(q3.x);
    acc.y += v0 * bf2f(q0.y) + v1 * bf2f(q1.y) + v2 * bf2f(q2.y) + v3 * bf2f(q3.y);
    acc.z += v0 * bf2f(q0.z) + v1 * bf2f(q1.z) + v2 * bf2f(q2.z) + v3 * bf2f(q3.z);
    acc.w += v0 * bf2f(q0.w) + v1 * bf2f(q1.w) + v2 * bf2f(q2.w) + v3 * bf2f(q3.w);
  }
  for (; e < hi; ++e) {
    float v = sval[e];
    ushort4 q = h4[(long)scol[e] * 16 + li];
    acc.x += v * bf2f(q.x);
    acc.y += v * bf2f(q.y);
    acc.z += v * bf2f(q.z);
    acc.w += v * bf2f(q.w);
  }
  float4* o = (float4*)(half ? outC : outS);
  o[(long)r * 16 + li] = acc;
}

// ---------------- fused dense chain (round-6 structure, known-good) -------
// H[n][64] (bf16) = relu(Ax@W1 + b1) @ W2. Inner loops identical to round 6;
// only the epilogue store casts to bf16.
__global__ __launch_bounds__(256) void fused_l1l2(
    const float* __restrict__ AxA, const float* __restrict__ AxB,
    const float* __restrict__ W1, const float* __restrict__ B1,
    const float* __restrict__ W2, ushort_t* __restrict__ H, int nrows) {
  __shared__ __attribute__((aligned(16))) float xs[32 * 128];
  __shared__ __attribute__((aligned(16))) float ws[64 * 128];
  int tid = threadIdx.x;
  long row0 = (long)blockIdx.x * 32;

  const float4* A4 = (const float4*)AxA;
  const float4* B4 = (const float4*)AxB;
  float4* xs4 = (float4*)xs;
#pragma unroll
  for (int i = 0; i < 4; ++i) {
    int flat = i * 256 + tid;
    int rl = flat >> 5, f4 = flat & 31;
    long rr = row0 + rl;
    float4 sv = make_float4(0.f, 0.f, 0.f, 0.f);
    if (rr < nrows)
      sv = (f4 < 16) ? A4[rr * 16 + f4] : B4[rr * 16 + (f4 - 16)];
    xs4[flat] = sv;
  }

  int c0 = tid & 63;
  int wv = tid >> 6;
  const float* xrow = xs + wv * 8 * 128;
  float acc0[8] = {}, acc1[8] = {};

  const float4* W14 = (const float4*)W1;
  float4* ws4 = (float4*)ws;
#pragma unroll
  for (int ph = 0; ph < 2; ++ph) {
    if (ph) __syncthreads();
#pragma unroll
    for (int i = 0; i < 8; ++i)
      ws4[i * 256 + tid] = W14[ph * 2048 + i * 256 + tid];
    __syncthreads();
#pragma unroll 4
    for (int k4 = 0; k4 < 16; ++k4) {
      float wa[4], wb[4];
#pragma unroll
      for (int j = 0; j < 4; ++j) {
        wa[j] = ws[(k4 * 4 + j) * 128 + c0];
        wb[j] = ws[(k4 * 4 + j) * 128 + c0 + 64];
      }
#pragma unroll
      for (int r = 0; r < 8; ++r) {
        float4 xv = *(const float4*)(xrow + r * 128 + ph * 64 + k4 * 4);
        acc0[r] += xv.x * wa[0] + xv.y * wa[1] + xv.z * wa[2] + xv.w * wa[3];
        acc1[r] += xv.x * wb[0] + xv.y * wb[1] + xv.z * wb[2] + xv.w * wb[3];
      }
    }
  }

  float b1a = B1[c0], b1b = B1[c0 + 64];
  __syncthreads();
#pragma unroll
  for (int r = 0; r < 8; ++r) {
    xs[(wv * 8 + r) * 128 + c0] = fmaxf(acc0[r] + b1a, 0.f);
    xs[(wv * 8 + r) * 128 + c0 + 64] = fmaxf(acc1[r] + b1b, 0.f);
  }

  const float4* W24 = (const float4*)W2;
#pragma unroll
  for (int i = 0; i < 8; ++i) ws4[i * 256 + tid] = W24[i * 256 + tid];
  __syncthreads();

  float acc2[8] = {};
#pragma unroll 4
  for (int k4 = 0; k4 < 32; ++k4) {
    float wk[4];
#pragma unroll
    for (int j = 0; j < 4; ++j) wk[j] = ws[(k4 * 4 + j) * 64 + c0];
#pragma unroll
    for (int r = 0; r < 8; ++r) {
      float4 xv = *(const float4*)(xrow + r * 128 + k4 * 4);
      acc2[r] += xv.x * wk[0] + xv.y * wk[1] + xv.z * wk[2] + xv.w * wk[3];
    }
  }
#pragma unroll
  for (int r = 0; r < 8; ++r) {
    long rr = row0 + wv * 8 + r;
    if (rr < nrows) H[rr * 64 + c0] = f2bf(acc2[r]);
  }
}

// ---------------- final fuse (16 lanes per node) ----------------
__global__ __launch_bounds__(256) void final_fuse(
    const float* __restrict__ emb1, const float* __restrict__ emb2,
    const float* __restrict__ com1, const float* __restrict__ com2,
    const float* __restrict__ attw1, const float* __restrict__ attb1,
    const float* __restrict__ attw2, const float* __restrict__ mlpw,
    const float* __restrict__ mlpb, float* __restrict__ out_logp,
    float* __restrict__ out_beta, float* __restrict__ out_emb, int n) {
  __shared__ __attribute__((aligned(16))) float w1t[16][64];
  __shared__ __attribute__((aligned(16))) float mwt[8][64];
  __shared__ float b1s[16];
  __shared__ float w2s[16];
  __shared__ float mbs[8];
  int tid = threadIdx.x;
  for (int idx = tid; idx < 1024; idx += 256)
    w1t[idx & 15][idx >> 4] = attw1[idx];
  for (int idx = tid; idx < 512; idx += 256)
    mwt[idx & 7][idx >> 3] = mlpw[idx];
  if (tid < 16) {
    b1s[tid] = attb1[tid];
    w2s[tid] = attw2[tid];
  }
  if (tid < 8) mbs[tid] = mlpb[tid];
  __syncthreads();

  int lane = tid & 15;
  long i = ((long)blockIdx.x * 256 + tid) >> 4;
  bool alive = i < n;
  long ii = alive ? i : (long)(n - 1);

  float4 z0 = ((const float4*)emb1)[ii * 16 + lane];
  float4 z1 = ((const float4*)emb2)[ii * 16 + lane];
  float4 x1 = ((const float4*)com1)[ii * 16 + lane];
  float4 x2 = ((const float4*)com2)[ii * 16 + lane];
  float4 z2 = make_float4(0.5f * (x1.x + x2.x), 0.5f * (x1.y + x2.y),
                          0.5f * (x1.z + x2.z), 0.5f * (x1.w + x2.w));

  float a0[16], a1[16], a2[16];
#pragma unroll
  for (int m = 0; m < 16; ++m) {
    float4 w = *(const float4*)&w1t[m][lane * 4];
    a0[m] = z0.x * w.x + z0.y * w.y + z0.z * w.z + z0.w * w.w;
    a1[m] = z1.x * w.x + z1.y * w.y + z1.z * w.z + z1.w * w.w;
    a2[m] = z2.x * w.x + z2.y * w.y + z2.z * w.z + z2.w * w.w;
  }
#pragma unroll
  for (int d = 1; d < 16; d <<= 1) {
#pragma unroll
    for (int m = 0; m < 16; ++m) {
      a0[m] += __shfl_xor(a0[m], d);
      a1[m] += __shfl_xor(a1[m], d);
      a2[m] += __shfl_xor(a2[m], d);
    }
  }
  float sc0 = 0.f, sc1 = 0.f, sc2 = 0.f;
#pragma unroll
  for (int m = 0; m < 16; ++m) {
    float wm = w2s[m], bm = b1s[m];
    sc0 += tanhf(a0[m] + bm) * wm;
    sc1 += tanhf(a1[m] + bm) * wm;
    sc2 += tanhf(a2[m] + bm) * wm;
  }
  float mx = fmaxf(sc0, fmaxf(sc1, sc2));
  float ex0 = expf(sc0 - mx), ex1 = expf(sc1 - mx), ex2 = expf(sc2 - mx);
  float inv = 1.f / (ex0 + ex1 + ex2);
  float be0 = ex0 * inv, be1 = ex1 * inv, be2 = ex2 * inv;

  float4 em;
  em.x = be0 * z0.x + be1 * z1.x + be2 * z2.x;
  em.y = be0 * z0.y + be1 * z1.y + be2 * z2.y;
  em.z = be0 * z0.z + be1 * z1.z + be2 * z2.z;
  em.w = be0 * z0.w + be1 * z1.w + be2 * z2.w;
  if (alive) ((float4*)out_emb)[i * 16 + lane] = em;

  float lg[8];
#pragma unroll
  for (int p = 0; p < 8; ++p) {
    float4 w = *(const float4*)&mwt[p][lane * 4];
    lg[p] = em.x * w.x + em.y * w.y + em.z * w.z + em.w * w.w;
  }
#pragma unroll
  for (int d = 1; d < 16; d <<= 1) {
#pragma unroll
    for (int p = 0; p < 8; ++p) lg[p] += __shfl_xor(lg[p], d);
  }
#pragma unroll
  for (int p = 0; p < 8; ++p) lg[p] += mbs[p];
  float m2 = lg[0];
#pragma unroll
  for (int p = 1; p < 8; ++p) m2 = fmaxf(m2, lg[p]);
  float ssum = 0.f;
#pragma unroll
  for (int p = 0; p < 8; ++p) ssum += expf(lg[p] - m2);
  float ls = m2 + logf(ssum);

  if (alive && lane == 0) {
    float4 o0 = make_float4(lg[0] - ls, lg[1] - ls, lg[2] - ls, lg[3] - ls);
    float4 o1 = make_float4(lg[4] - ls, lg[5] - ls, lg[6] - ls, lg[7] - ls);
    *(float4*)&out_logp[i * 8] = o0;
    *(float4*)&out_logp[i * 8 + 4] = o1;
    out_beta[i * 3 + 0] = be0;
    out_beta[i * 3 + 1] = be1;
    out_beta[i * 3 + 2] = be2;
  }
}

extern "C" void kernel_launch(void* const* d_in, const int* in_sizes, int n_in,
                              void* d_out, int out_size, void* d_ws,
                              size_t ws_size, hipStream_t stream) {
  const float* x = (const float*)d_in[0];
  const int* srow = (const int*)d_in[1];
  const int* scol_in = (const int*)d_in[2];
  const float* sval_in = (const float*)d_in[3];
  const int* frow = (const int*)d_in[4];
  const int* fcol_in = (const int*)d_in[5];
  const float* fval_in = (const float*)d_in[6];
  const float* w_s1_1 = (const float*)d_in[7];
  const float* b_s1_1 = (const float*)d_in[8];
  const float* w_s1_2 = (const float*)d_in[9];
  const float* b_s1_2 = (const float*)d_in[10];
  const float* w_s2_1 = (const float*)d_in[11];
  const float* b_s2_1 = (const float*)d_in[12];
  const float* w_s2_2 = (const float*)d_in[13];
  const float* b_s2_2 = (const float*)d_in[14];
  const float* w_c_1 = (const float*)d_in[15];
  const float* b_c_1 = (const float*)d_in[16];
  const float* w_c_2 = (const float*)d_in[17];
  const float* b_c_2 = (const float*)d_in[18];
  const float* attw1 = (const float*)d_in[19];
  const float* attb1 = (const float*)d_in[20];
  const float* attw2 = (const float*)d_in[21];
  const float* mlpw = (const float*)d_in[22];
  const float* mlpb = (const float*)d_in[23];

  const int n = in_sizes[0] / 128;  // 100000
  const int e = in_sizes[1];        // 1600000

  float* out = (float*)d_out;
  float* o_logp = out;
  float* o_beta = out + (size_t)n * 8;
  float* o_emb1 = out + (size_t)n * 11;
  float* o_com1 = o_emb1 + (size_t)n * 64;
  float* o_com2 = o_com1 + (size_t)n * 64;
  float* o_emb2 = o_com2 + (size_t)n * 64;
  float* o_emb = o_emb2 + (size_t)n * 64;

  // x_bf16 (n*128 bf16 = 25.6MB) lives in the o_emb region (n*64 f32 =
  // 25.6MB, exact fit); final_fuse overwrites it at the very end.
  ushort_t* x_bf16 = (ushort_t*)o_emb;

  // workspace layout (~90.8MB, within proven 102.4MB budget)
  float* axA = (float*)d_ws;                         // n*64 f32
  float* axB = axA + (size_t)n * 64;                 // n*64 f32
  ushort_t* hwS = (ushort_t*)(axB + (size_t)n * 64); // n*64 bf16
  ushort_t* hwC = hwS + (size_t)n * 64;              // n*64 bf16
  int* cnt = (int*)(hwC + (size_t)n * 64);           // n
  int* rowptr = cnt + n;                             // n+1
  int* woff = rowptr + n + 1;                        // n
  int* part = woff + n;                              // <=256
  int* g_col = part + 256;                           // e
  float* g_val = (float*)(g_col + e);                // e

  const int gemmBlocks = (n + 31) / 32;
  const int histBlocks = (e + 255) / 256;
  const int scanBlocks = (n + 1023) / 1024;
  const int spmmBlocks = (n + 7) / 8;
  const int cvtBlocks = (int)(((long)n * 32 + 255) / 256);

  auto build_csr = [&](const int* r, const int* c, const float* v) {
    hipMemsetAsync(cnt, 0, (size_t)n * sizeof(int), stream);
    hist_kernel<<<histBlocks, 256, 0, stream>>>(r, cnt, e);
    scan_partial<<<scanBlocks, 256, 0, stream>>>(cnt, part, n);
    scan_tops<<<1, 256, 0, stream>>>(part, scanBlocks);
    scan_final<<<scanBlocks, 256, 0, stream>>>(cnt, part, rowptr, woff, n, e);
    scatter_kernel<<<histBlocks, 256, 0, stream>>>(r, c, v, woff, g_col,
                                                   g_val, e);
  };

  // x -> bf16 once
  cvt_bf16<<<cvtBlocks, 256, 0, stream>>>(x, x_bf16, (long)n * 32);

  // --- graph sadj: emb1 (w_s1) + com1 (w_c) ---
  build_csr(srow, scol_in, sval_in);
  spmm_csr_128<<<spmmBlocks, 256, 0, stream>>>(rowptr, g_col, g_val, x_bf16,
                                               axA, axB, n);
  fused_l1l2<<<gemmBlocks, 256, 0, stream>>>(axA, axB, w_s1_1, b_s1_1, w_s1_2,
                                             hwS, n);
  fused_l1l2<<<gemmBlocks, 256, 0, stream>>>(axA, axB, w_c_1, b_c_1, w_c_2,
                                             hwC, n);
  spmm_dual64<<<spmmBlocks, 256, 0, stream>>>(rowptr, g_col, g_val, hwS, hwC,
                                              b_s1_2, b_c_2, o_emb1, o_com1,
                                              n);

  // --- graph fadj: com2 (w_c) + emb2 (w_s2) ---
  build_csr(frow, fcol_in, fval_in);
  spmm_csr_128<<<spmmBlocks, 256, 0, stream>>>(rowptr, g_col, g_val, x_bf16,
                                               axA, axB, n);
  fused_l1l2<<<gemmBlocks, 256, 0, stream>>>(axA, axB, w_s2_1, b_s2_1, w_s2_2,
                                             hwS, n);
  fused_l1l2<<<gemmBlocks, 256, 0, stream>>>(axA, axB, w_c_1, b_c_1, w_c_2,
                                             hwC, n);
  spmm_dual64<<<spmmBlocks, 256, 0, stream>>>(rowptr, g_col, g_val, hwS, hwC,
                                              b_s2_2, b_c_2, o_emb2, o_com2,
                                              n);

  final_fuse<<<(int)(((long)n * 16 + 255) / 256), 256, 0, stream>>>(
      o_emb1, o_emb2, o_com1, o_com2, attw1, attb1, attw2, mlpw, mlpb, o_logp,
      o_beta, o_emb, n);
}

// Round 10
// 856.469 us; speedup vs baseline: 5.5511x; 1.4281x over previous
//
#include <hip/hip_runtime.h>

// ---------------------------------------------------------------------------
// SFGCN forward on MI355X, round 10:
//  - fused_l1l2 -> bf16 MFMA (mfma_f32_16x16x32_bf16). GEMM1 computed flipped
//    (S^T = W1T x Ax^T) so A/B frags are contiguous-K b128 loads AND the
//    C-frag packs 4 contiguous sfeats/lane -> S' to LDS via ds_write_b64.
//    GEMM2 standard (H = S' @ W2 via pre-transposed W2T). fp32 VALU chain
//    (143us, 3x FMA-count instr overhead) -> matrix pipe (~3us compute floor).
//  - spmm_csr_128 emits Ax as bf16 directly (single [n][128] array).
//  - prep_weights: one tiny kernel builds bf16 W1T/W2T for all 3 weight sets.
// ---------------------------------------------------------------------------

typedef unsigned short ushort_t;
typedef float f32x4 __attribute__((ext_vector_type(4)));
typedef short short8 __attribute__((ext_vector_type(8)));

__device__ __forceinline__ ushort_t f2bf(float f) {  // round-to-nearest-even
  unsigned u = __float_as_uint(f);
  unsigned r = (u + 0x7FFFu + ((u >> 16) & 1u)) >> 16;
  return (ushort_t)r;
}
__device__ __forceinline__ float bf2f(ushort_t b) {
  return __uint_as_float((unsigned)b << 16);
}

// total4 float4 chunks -> ushort4 bf16 chunks
__global__ __launch_bounds__(256) void cvt_bf16(
    const float* __restrict__ in, ushort_t* __restrict__ out, long total4) {
  long i = (long)blockIdx.x * 256 + threadIdx.x;
  if (i >= total4) return;
  float4 v = ((const float4*)in)[i];
  ushort4 o;
  o.x = f2bf(v.x);
  o.y = f2bf(v.y);
  o.z = f2bf(v.z);
  o.w = f2bf(v.w);
  ((ushort4*)out)[i] = o;
}

// Transpose+cast the 3 weight pairs to bf16: W1T[nn][k]=W1[k][nn] (128x128),
// W2T[h][k]=W2[k][h] (64x128). grid = 288 blocks x 256.
__global__ __launch_bounds__(256) void prep_weights(
    const float* __restrict__ w1a, const float* __restrict__ w1b,
    const float* __restrict__ w1c, const float* __restrict__ w2a,
    const float* __restrict__ w2b, const float* __restrict__ w2c,
    ushort_t* __restrict__ o1a, ushort_t* __restrict__ o1b,
    ushort_t* __restrict__ o1c, ushort_t* __restrict__ o2a,
    ushort_t* __restrict__ o2b, ushort_t* __restrict__ o2c) {
  int i = blockIdx.x * 256 + threadIdx.x;
  if (i < 49152) {  // 3 x 128x128
    int a = i >> 14, j = i & 16383;
    int nn = j >> 7, k = j & 127;
    const float* s = (a == 0) ? w1a : (a == 1) ? w1b : w1c;
    ushort_t* d = (a == 0) ? o1a : (a == 1) ? o1b : o1c;
    d[j] = f2bf(s[k * 128 + nn]);
  } else if (i < 73728) {  // 3 x 64x128
    int i2 = i - 49152;
    int a = i2 >> 13, j = i2 & 8191;
    int h = j >> 7, k = j & 127;
    const float* s = (a == 0) ? w2a : (a == 1) ? w2b : w2c;
    ushort_t* d = (a == 0) ? o2a : (a == 1) ? o2b : o2c;
    d[j] = f2bf(s[k * 64 + h]);
  }
}

// ---------------- CSR build ----------------

__global__ __launch_bounds__(256) void hist_kernel(
    const int* __restrict__ row, int* __restrict__ cnt, int e) {
  int i = blockIdx.x * 256 + threadIdx.x;
  if (i < e) atomicAdd(&cnt[row[i]], 1);
}

__global__ __launch_bounds__(256) void scan_partial(
    const int* __restrict__ cnt, int* __restrict__ part, int n) {
  __shared__ int red[256];
  int t = threadIdx.x;
  int base = blockIdx.x * 1024 + t * 4;
  int s = 0;
#pragma unroll
  for (int j = 0; j < 4; ++j) {
    int idx = base + j;
    if (idx < n) s += cnt[idx];
  }
  red[t] = s;
  __syncthreads();
#pragma unroll
  for (int d = 128; d > 0; d >>= 1) {
    if (t < d) red[t] += red[t + d];
    __syncthreads();
  }
  if (t == 0) part[blockIdx.x] = red[0];
}

__global__ __launch_bounds__(256) void scan_tops(int* __restrict__ part,
                                                 int nb) {
  __shared__ int lds[256];
  int t = threadIdx.x;
  lds[t] = (t < nb) ? part[t] : 0;
  __syncthreads();
#pragma unroll
  for (int d = 1; d < 256; d <<= 1) {
    int v = (t >= d) ? lds[t - d] : 0;
    __syncthreads();
    lds[t] += v;
    __syncthreads();
  }
  if (t < nb) part[t] = (t == 0) ? 0 : lds[t - 1];
}

__global__ __launch_bounds__(256) void scan_final(
    const int* __restrict__ cnt, const int* __restrict__ part,
    int* __restrict__ rowptr, int* __restrict__ woff, int n, int e) {
  __shared__ int lds[256];
  int t = threadIdx.x;
  int base = blockIdx.x * 1024 + t * 4;
  int c[4];
  int s = 0;
#pragma unroll
  for (int j = 0; j < 4; ++j) {
    int idx = base + j;
    c[j] = (idx < n) ? cnt[idx] : 0;
    s += c[j];
  }
  lds[t] = s;
  __syncthreads();
#pragma unroll
  for (int d = 1; d < 256; d <<= 1) {
    int v = (t >= d) ? lds[t - d] : 0;
    __syncthreads();
    lds[t] += v;
    __syncthreads();
  }
  int off = part[blockIdx.x] + ((t == 0) ? 0 : lds[t - 1]);
#pragma unroll
  for (int j = 0; j < 4; ++j) {
    int idx = base + j;
    if (idx < n) {
      rowptr[idx] = off;
      woff[idx] = off;
      off += c[j];
    }
  }
  if (blockIdx.x == 0 && t == 0) rowptr[n] = e;
}

__global__ __launch_bounds__(256) void scatter_kernel(
    const int* __restrict__ row, const int* __restrict__ col,
    const float* __restrict__ val, int* __restrict__ woff,
    int* __restrict__ scol, float* __restrict__ sval, int e) {
  int i = blockIdx.x * 256 + threadIdx.x;
  if (i >= e) return;
  int r = row[i];
  int p = atomicAdd(&woff[r], 1);
  scol[p] = col[i];
  sval[p] = val[i];
}

// ---------------- CSR SpMM (bf16 gather, fp32 accumulate) ----------------

// 128 feats: 32 lanes/row, bf16 gather, edge-unroll x4; OUTPUT = bf16 [n][128].
__global__ __launch_bounds__(256) void spmm_csr_128(
    const int* __restrict__ rowptr, const int* __restrict__ scol,
    const float* __restrict__ sval, const ushort_t* __restrict__ h,
    ushort_t* __restrict__ Ax, int n) {
  int tid = threadIdx.x;
  int r = blockIdx.x * 8 + (tid >> 5);
  if (r >= n) return;
  int lane = tid & 31;
  int lo = rowptr[r], hi = rowptr[r + 1];
  const ushort4* h4 = (const ushort4*)h;  // row stride = 32 ushort4
  float4 acc = make_float4(0.f, 0.f, 0.f, 0.f);
  int e = lo;
  for (; e + 4 <= hi; e += 4) {
    int c0 = scol[e], c1 = scol[e + 1], c2 = scol[e + 2], c3 = scol[e + 3];
    float v0 = sval[e], v1 = sval[e + 1], v2 = sval[e + 2], v3 = sval[e + 3];
    ushort4 q0 = h4[(long)c0 * 32 + lane];
    ushort4 q1 = h4[(long)c1 * 32 + lane];
    ushort4 q2 = h4[(long)c2 * 32 + lane];
    ushort4 q3 = h4[(long)c3 * 32 + lane];
    acc.x += v0 * bf2f(q0.x) + v1 * bf2f(q1.x) + v2 * bf2f(q2.x) + v3 * bf2f(q3.x);
    acc.y += v0 * bf2f(q0.y) + v1 * bf2f(q1.y) + v2 * bf2f(q2.y) + v3 * bf2f(q3.y);
    acc.z += v0 * bf2f(q0.z) + v1 * bf2f(q1.z) + v2 * bf2f(q2.z) + v3 * bf2f(q3.z);
    acc.w += v0 * bf2f(q0.w) + v1 * bf2f(q1.w) + v2 * bf2f(q2.w) + v3 * bf2f(q3.w);
  }
  for (; e < hi; ++e) {
    float v = sval[e];
    ushort4 q = h4[(long)scol[e] * 32 + lane];
    acc.x += v * bf2f(q.x);
    acc.y += v * bf2f(q.y);
    acc.z += v * bf2f(q.z);
    acc.w += v * bf2f(q.w);
  }
  ushort4 o;
  o.x = f2bf(acc.x);
  o.y = f2bf(acc.y);
  o.z = f2bf(acc.z);
  o.w = f2bf(acc.w);
  ((ushort4*)Ax)[(long)r * 32 + lane] = o;
}

// Dual 64-feat SpMM, bf16 gather: lanes 0-15 -> hS/outS(+bS), 16-31 -> hC.
__global__ __launch_bounds__(256) void spmm_dual64(
    const int* __restrict__ rowptr, const int* __restrict__ scol,
    const float* __restrict__ sval, const ushort_t* __restrict__ hS,
    const ushort_t* __restrict__ hC, const float* __restrict__ bS,
    const float* __restrict__ bC, float* __restrict__ outS,
    float* __restrict__ outC, int n) {
  int tid = threadIdx.x;
  int r = blockIdx.x * 8 + (tid >> 5);
  if (r >= n) return;
  int lane = tid & 31;
  int half = lane >> 4;
  int li = lane & 15;
  const ushort4* h4 = (const ushort4*)(half ? hC : hS);  // row = 16 ushort4
  float4 acc = ((const float4*)(half ? bC : bS))[li];
  int lo = rowptr[r], hi = rowptr[r + 1];
  int e = lo;
  for (; e + 4 <= hi; e += 4) {
    int c0 = scol[e], c1 = scol[e + 1], c2 = scol[e + 2], c3 = scol[e + 3];
    float v0 = sval[e], v1 = sval[e + 1], v2 = sval[e + 2], v3 = sval[e + 3];
    ushort4 q0 = h4[(long)c0 * 16 + li];
    ushort4 q1 = h4[(long)c1 * 16 + li];
    ushort4 q2 = h4[(long)c2 * 16 + li];
    ushort4 q3 = h4[(long)c3 * 16 + li];
    acc.x += v0 * bf2f(q0.x) + v1 * bf2f(q1.x) + v2 * bf2f(q2.x) + v3 * bf2f(q3.x);
    acc.y += v0 * bf2f(q0.y) + v1 * bf2f(q1.y) + v2 * bf2f(q2.y) + v3 * bf2f(q3.y);
    acc.z += v0 * bf2f(q0.z) + v1 * bf2f(q1.z) + v2 * bf2f(q2.z) + v3 * bf2f(q3.z);
    acc.w += v0 * bf2f(q0.w) + v1 * bf2f(q1.w) + v2 * bf2f(q2.w) + v3 * bf2f(q3.w);
  }
  for (; e < hi; ++e) {
    float v = sval[e];
    ushort4 q = h4[(long)scol[e] * 16 + li];
    acc.x += v * bf2f(q.x);
    acc.y += v * bf2f(q.y);
    acc.z += v * bf2f(q.z);
    acc.w += v * bf2f(q.w);
  }
  float4* o = (float4*)(half ? outC : outS);
  o[(long)r * 16 + li] = acc;
}

// ---------------- fused dense chain, bf16 MFMA ----------------
// H[n][64] (bf16) = relu(Ax@W1 + b1) @ W2.
// Per block: 64 node rows, 4 waves.
//  GEMM1 (flipped): S^T = W1T x Ax^T. wave w: sfeat rows [32w,32w+32)
//    (2 M-frags), nodes = all 64 (4 N-frags), K=128 (4 k-tiles).
//    A-frag: W1T[sfeat][k] b128; B-frag: Ax[node][k] b128 (both contiguous-K).
//    C: lane(lo16)=node-col, sfeat = 32w+16m+4g+r -> 4 contiguous sfeats/lane
//    -> relu+bias -> pack ushort4 -> ONE ds_write_b64 per frag into S'.
//  GEMM2 (standard): H = S' @ W2. wave w: node rows [16w,16w+16), hfeat 64,
//    K=128. A-frag: S'[node][k] b128 LDS; B-frag: W2T[hcol][k] b128.
__global__ __launch_bounds__(256) void fused_l1l2_mfma(
    const ushort_t* __restrict__ Ax,   // [n][128] bf16
    const ushort_t* __restrict__ W1T,  // [128][128] bf16 (W1T[nn][k]=W1[k][nn])
    const float* __restrict__ B1,      // [128] f32
    const ushort_t* __restrict__ W2T,  // [64][128] bf16 (W2T[h][k]=W2[k][h])
    ushort_t* __restrict__ H,          // [n][64] bf16
    int n) {
  __shared__ __attribute__((aligned(16))) ushort_t sp[64][136];  // S' (+pad)
  int tid = threadIdx.x;
  int w = tid >> 6;
  int l = tid & 63;
  int lo16 = l & 15;
  int g = l >> 4;
  long node0 = (long)blockIdx.x * 64;

  // ---- GEMM1 (flipped) ----
  f32x4 acc1[2][4];
#pragma unroll
  for (int m = 0; m < 2; ++m)
#pragma unroll
    for (int nu = 0; nu < 4; ++nu) acc1[m][nu] = (f32x4){0.f, 0.f, 0.f, 0.f};

#pragma unroll 1
  for (int t = 0; t < 4; ++t) {
    short8 af0 = *(const short8*)(W1T + (32 * w + lo16) * 128 + 32 * t + 8 * g);
    short8 af1 =
        *(const short8*)(W1T + (32 * w + 16 + lo16) * 128 + 32 * t + 8 * g);
#pragma unroll
    for (int nu = 0; nu < 4; ++nu) {
      long node = node0 + 16 * nu + lo16;
      if (node > (long)n - 1) node = (long)n - 1;
      short8 bf = *(const short8*)(Ax + node * 128 + 32 * t + 8 * g);
      acc1[0][nu] =
          __builtin_amdgcn_mfma_f32_16x16x32_bf16(af0, bf, acc1[0][nu], 0, 0, 0);
      acc1[1][nu] =
          __builtin_amdgcn_mfma_f32_16x16x32_bf16(af1, bf, acc1[1][nu], 0, 0, 0);
    }
  }

  // relu + bias, pack 4 contiguous sfeats -> S' LDS (row-major [node][sfeat])
#pragma unroll
  for (int m = 0; m < 2; ++m) {
    int sf = 32 * w + 16 * m + 4 * g;
    float4 b1v = *(const float4*)(B1 + sf);
#pragma unroll
    for (int nu = 0; nu < 4; ++nu) {
      int node_l = 16 * nu + lo16;
      ushort4 pk;
      pk.x = f2bf(fmaxf(acc1[m][nu][0] + b1v.x, 0.f));
      pk.y = f2bf(fmaxf(acc1[m][nu][1] + b1v.y, 0.f));
      pk.z = f2bf(fmaxf(acc1[m][nu][2] + b1v.z, 0.f));
      pk.w = f2bf(fmaxf(acc1[m][nu][3] + b1v.w, 0.f));
      *(ushort4*)(&sp[node_l][sf]) = pk;
    }
  }
  __syncthreads();

  // ---- GEMM2 (standard) ----
  f32x4 acc2[4];
#pragma unroll
  for (int nu = 0; nu < 4; ++nu) acc2[nu] = (f32x4){0.f, 0.f, 0.f, 0.f};
#pragma unroll 1
  for (int t = 0; t < 4; ++t) {
    short8 af = *(const short8*)(&sp[16 * w + lo16][32 * t + 8 * g]);
#pragma unroll
    for (int nu = 0; nu < 4; ++nu) {
      short8 bf =
          *(const short8*)(W2T + (16 * nu + lo16) * 128 + 32 * t + 8 * g);
      acc2[nu] =
          __builtin_amdgcn_mfma_f32_16x16x32_bf16(af, bf, acc2[nu], 0, 0, 0);
    }
  }
  // store H: node = node0 + 16w + 4g + r, hcol = 16nu + lo16
#pragma unroll
  for (int nu = 0; nu < 4; ++nu) {
#pragma unroll
    for (int r = 0; r < 4; ++r) {
      long node = node0 + 16 * w + 4 * g + r;
      if (node < n) H[node * 64 + 16 * nu + lo16] = f2bf(acc2[nu][r]);
    }
  }
}

// ---------------- final fuse (16 lanes per node) ----------------
__global__ __launch_bounds__(256) void final_fuse(
    const float* __restrict__ emb1, const float* __restrict__ emb2,
    const float* __restrict__ com1, const float* __restrict__ com2,
    const float* __restrict__ attw1, const float* __restrict__ attb1,
    const float* __restrict__ attw2, const float* __restrict__ mlpw,
    const float* __restrict__ mlpb, float* __restrict__ out_logp,
    float* __restrict__ out_beta, float* __restrict__ out_emb, int n) {
  __shared__ __attribute__((aligned(16))) float w1t[16][64];
  __shared__ __attribute__((aligned(16))) float mwt[8][64];
  __shared__ float b1s[16];
  __shared__ float w2s[16];
  __shared__ float mbs[8];
  int tid = threadIdx.x;
  for (int idx = tid; idx < 1024; idx += 256)
    w1t[idx & 15][idx >> 4] = attw1[idx];
  for (int idx = tid; idx < 512; idx += 256)
    mwt[idx & 7][idx >> 3] = mlpw[idx];
  if (tid < 16) {
    b1s[tid] = attb1[tid];
    w2s[tid] = attw2[tid];
  }
  if (tid < 8) mbs[tid] = mlpb[tid];
  __syncthreads();

  int lane = tid & 15;
  long i = ((long)blockIdx.x * 256 + tid) >> 4;
  bool alive = i < n;
  long ii = alive ? i : (long)(n - 1);

  float4 z0 = ((const float4*)emb1)[ii * 16 + lane];
  float4 z1 = ((const float4*)emb2)[ii * 16 + lane];
  float4 x1 = ((const float4*)com1)[ii * 16 + lane];
  float4 x2 = ((const float4*)com2)[ii * 16 + lane];
  float4 z2 = make_float4(0.5f * (x1.x + x2.x), 0.5f * (x1.y + x2.y),
                          0.5f * (x1.z + x2.z), 0.5f * (x1.w + x2.w));

  float a0[16], a1[16], a2[16];
#pragma unroll
  for (int m = 0; m < 16; ++m) {
    float4 w = *(const float4*)&w1t[m][lane * 4];
    a0[m] = z0.x * w.x + z0.y * w.y + z0.z * w.z + z0.w * w.w;
    a1[m] = z1.x * w.x + z1.y * w.y + z1.z * w.z + z1.w * w.w;
    a2[m] = z2.x * w.x + z2.y * w.y + z2.z * w.z + z2.w * w.w;
  }
#pragma unroll
  for (int d = 1; d < 16; d <<= 1) {
#pragma unroll
    for (int m = 0; m < 16; ++m) {
      a0[m] += __shfl_xor(a0[m], d);
      a1[m] += __shfl_xor(a1[m], d);
      a2[m] += __shfl_xor(a2[m], d);
    }
  }
  float sc0 = 0.f, sc1 = 0.f, sc2 = 0.f;
#pragma unroll
  for (int m = 0; m < 16; ++m) {
    float wm = w2s[m], bm = b1s[m];
    sc0 += tanhf(a0[m] + bm) * wm;
    sc1 += tanhf(a1[m] + bm) * wm;
    sc2 += tanhf(a2[m] + bm) * wm;
  }
  float mx = fmaxf(sc0, fmaxf(sc1, sc2));
  float ex0 = expf(sc0 - mx), ex1 = expf(sc1 - mx), ex2 = expf(sc2 - mx);
  float inv = 1.f / (ex0 + ex1 + ex2);
  float be0 = ex0 * inv, be1 = ex1 * inv, be2 = ex2 * inv;

  float4 em;
  em.x = be0 * z0.x + be1 * z1.x + be2 * z2.x;
  em.y = be0 * z0.y + be1 * z1.y + be2 * z2.y;
  em.z = be0 * z0.z + be1 * z1.z + be2 * z2.z;
  em.w = be0 * z0.w + be1 * z1.w + be2 * z2.w;
  if (alive) ((float4*)out_emb)[i * 16 + lane] = em;

  float lg[8];
#pragma unroll
  for (int p = 0; p < 8; ++p) {
    float4 w = *(const float4*)&mwt[p][lane * 4];
    lg[p] = em.x * w.x + em.y * w.y + em.z * w.z + em.w * w.w;
  }
#pragma unroll
  for (int d = 1; d < 16; d <<= 1) {
#pragma unroll
    for (int p = 0; p < 8; ++p) lg[p] += __shfl_xor(lg[p], d);
  }
#pragma unroll
  for (int p = 0; p < 8; ++p) lg[p] += mbs[p];
  float m2 = lg[0];
#pragma unroll
  for (int p = 1; p < 8; ++p) m2 = fmaxf(m2, lg[p]);
  float ssum = 0.f;
#pragma unroll
  for (int p = 0; p < 8; ++p) ssum += expf(lg[p] - m2);
  float ls = m2 + logf(ssum);

  if (alive && lane == 0) {
    float4 o0 = make_float4(lg[0] - ls, lg[1] - ls, lg[2] - ls, lg[3] - ls);
    float4 o1 = make_float4(lg[4] - ls, lg[5] - ls, lg[6] - ls, lg[7] - ls);
    *(float4*)&out_logp[i * 8] = o0;
    *(float4*)&out_logp[i * 8 + 4] = o1;
    out_beta[i * 3 + 0] = be0;
    out_beta[i * 3 + 1] = be1;
    out_beta[i * 3 + 2] = be2;
  }
}

extern "C" void kernel_launch(void* const* d_in, const int* in_sizes, int n_in,
                              void* d_out, int out_size, void* d_ws,
                              size_t ws_size, hipStream_t stream) {
  const float* x = (const float*)d_in[0];
  const int* srow = (const int*)d_in[1];
  const int* scol_in = (const int*)d_in[2];
  const float* sval_in = (const float*)d_in[3];
  const int* frow = (const int*)d_in[4];
  const int* fcol_in = (const int*)d_in[5];
  const float* fval_in = (const float*)d_in[6];
  const float* w_s1_1 = (const float*)d_in[7];
  const float* b_s1_1 = (const float*)d_in[8];
  const float* w_s1_2 = (const float*)d_in[9];
  const float* b_s1_2 = (const float*)d_in[10];
  const float* w_s2_1 = (const float*)d_in[11];
  const float* b_s2_1 = (const float*)d_in[12];
  const float* w_s2_2 = (const float*)d_in[13];
  const float* b_s2_2 = (const float*)d_in[14];
  const float* w_c_1 = (const float*)d_in[15];
  const float* b_c_1 = (const float*)d_in[16];
  const float* w_c_2 = (const float*)d_in[17];
  const float* b_c_2 = (const float*)d_in[18];
  const float* attw1 = (const float*)d_in[19];
  const float* attb1 = (const float*)d_in[20];
  const float* attw2 = (const float*)d_in[21];
  const float* mlpw = (const float*)d_in[22];
  const float* mlpb = (const float*)d_in[23];

  const int n = in_sizes[0] / 128;  // 100000
  const int e = in_sizes[1];        // 1600000

  float* out = (float*)d_out;
  float* o_logp = out;
  float* o_beta = out + (size_t)n * 8;
  float* o_emb1 = out + (size_t)n * 11;
  float* o_com1 = o_emb1 + (size_t)n * 64;
  float* o_com2 = o_com1 + (size_t)n * 64;
  float* o_emb2 = o_com2 + (size_t)n * 64;
  float* o_emb = o_emb2 + (size_t)n * 64;

  // x_bf16 (n*128 bf16 = 25.6MB) lives in the o_emb region (exact fit);
  // final_fuse overwrites it at the very end.
  ushort_t* x_bf16 = (ushort_t*)o_emb;

  // workspace layout (~65MB, within proven 102.4MB budget)
  ushort_t* ax = (ushort_t*)d_ws;                 // n*128 bf16
  ushort_t* hwS = ax + (size_t)n * 128;           // n*64 bf16
  ushort_t* hwC = hwS + (size_t)n * 64;           // n*64 bf16
  ushort_t* w1t_s1 = hwC + (size_t)n * 64;        // 128*128 bf16
  ushort_t* w1t_s2 = w1t_s1 + 16384;
  ushort_t* w1t_c = w1t_s2 + 16384;
  ushort_t* w2t_s1 = w1t_c + 16384;               // 64*128 bf16
  ushort_t* w2t_s2 = w2t_s1 + 8192;
  ushort_t* w2t_c = w2t_s2 + 8192;
  int* cnt = (int*)(w2t_c + 8192);                // n
  int* rowptr = cnt + n;                          // n+1
  int* woff = rowptr + n + 1;                     // n
  int* part = woff + n;                           // <=256 (+1 pad for align)
  int* g_col = part + 256;                        // e
  float* g_val = (float*)(g_col + e);             // e

  const int histBlocks = (e + 255) / 256;
  const int scanBlocks = (n + 1023) / 1024;
  const int spmmBlocks = (n + 7) / 8;
  const int cvtBlocks = (int)(((long)n * 32 + 255) / 256);
  const int mfmaBlocks = (n + 63) / 64;

  auto build_csr = [&](const int* r, const int* c, const float* v) {
    hipMemsetAsync(cnt, 0, (size_t)n * sizeof(int), stream);
    hist_kernel<<<histBlocks, 256, 0, stream>>>(r, cnt, e);
    scan_partial<<<scanBlocks, 256, 0, stream>>>(cnt, part, n);
    scan_tops<<<1, 256, 0, stream>>>(part, scanBlocks);
    scan_final<<<scanBlocks, 256, 0, stream>>>(cnt, part, rowptr, woff, n, e);
    scatter_kernel<<<histBlocks, 256, 0, stream>>>(r, c, v, woff, g_col,
                                                   g_val, e);
  };

  // one-time preprocessing
  cvt_bf16<<<cvtBlocks, 256, 0, stream>>>(x, x_bf16, (long)n * 32);
  prep_weights<<<288, 256, 0, stream>>>(w_s1_1, w_s2_1, w_c_1, w_s1_2, w_s2_2,
                                        w_c_2, w1t_s1, w1t_s2, w1t_c, w2t_s1,
                                        w2t_s2, w2t_c);

  // --- graph sadj: emb1 (w_s1) + com1 (w_c) ---
  build_csr(srow, scol_in, sval_in);
  spmm_csr_128<<<spmmBlocks, 256, 0, stream>>>(rowptr, g_col, g_val, x_bf16,
                                               ax, n);
  fused_l1l2_mfma<<<mfmaBlocks, 256, 0, stream>>>(ax, w1t_s1, b_s1_1, w2t_s1,
                                                  hwS, n);
  fused_l1l2_mfma<<<mfmaBlocks, 256, 0, stream>>>(ax, w1t_c, b_c_1, w2t_c,
                                                  hwC, n);
  spmm_dual64<<<spmmBlocks, 256, 0, stream>>>(rowptr, g_col, g_val, hwS, hwC,
                                              b_s1_2, b_c_2, o_emb1, o_com1,
                                              n);

  // --- graph fadj: com2 (w_c) + emb2 (w_s2) ---
  build_csr(frow, fcol_in, fval_in);
  spmm_csr_128<<<spmmBlocks, 256, 0, stream>>>(rowptr, g_col, g_val, x_bf16,
                                               ax, n);
  fused_l1l2_mfma<<<mfmaBlocks, 256, 0, stream>>>(ax, w1t_s2, b_s2_1, w2t_s2,
                                                  hwS, n);
  fused_l1l2_mfma<<<mfmaBlocks, 256, 0, stream>>>(ax, w1t_c, b_c_1, w2t_c,
                                                  hwC, n);
  spmm_dual64<<<spmmBlocks, 256, 0, stream>>>(rowptr, g_col, g_val, hwS, hwC,
                                              b_s2_2, b_c_2, o_emb2, o_com2,
                                              n);

  final_fuse<<<(int)(((long)n * 16 + 255) / 256), 256, 0, stream>>>(
      o_emb1, o_emb2, o_com1, o_com2, attw1, attb1, attw2, mlpw, mlpb, o_logp,
      o_beta, o_emb, n);
}

// Round 11
// 853.522 us; speedup vs baseline: 5.5702x; 1.0035x over previous
//
#include <hip/hip_runtime.h>

// ---------------------------------------------------------------------------
// SFGCN forward on MI355X, round 11:
//  - SINGLE merged CSR build for BOTH graphs: cntS||cntF (2n), one scan
//    (rowptr[2n]=2e), one hist + one scatter over 2e edges. fadj rows use
//    rowptr+n; packed edge buffer shared (sadj in [0,e), fadj in [e,2e)).
//  - PACKED int2 (col, val-bits) edge records: 1x8B random scatter store per
//    edge (was 2x4B into two arrays -> 153MB HBM writes); SpMM metadata
//    becomes one 8B load per edge.
//  - MFMA dense chain, bf16 gathers, wave-coop final_fuse unchanged.
// ---------------------------------------------------------------------------

typedef unsigned short ushort_t;
typedef float f32x4 __attribute__((ext_vector_type(4)));
typedef short short8 __attribute__((ext_vector_type(8)));

__device__ __forceinline__ ushort_t f2bf(float f) {  // round-to-nearest-even
  unsigned u = __float_as_uint(f);
  unsigned r = (u + 0x7FFFu + ((u >> 16) & 1u)) >> 16;
  return (ushort_t)r;
}
__device__ __forceinline__ float bf2f(ushort_t b) {
  return __uint_as_float((unsigned)b << 16);
}

// total4 float4 chunks -> ushort4 bf16 chunks
__global__ __launch_bounds__(256) void cvt_bf16(
    const float* __restrict__ in, ushort_t* __restrict__ out, long total4) {
  long i = (long)blockIdx.x * 256 + threadIdx.x;
  if (i >= total4) return;
  float4 v = ((const float4*)in)[i];
  ushort4 o;
  o.x = f2bf(v.x);
  o.y = f2bf(v.y);
  o.z = f2bf(v.z);
  o.w = f2bf(v.w);
  ((ushort4*)out)[i] = o;
}

// Transpose+cast the 3 weight pairs to bf16: W1T[nn][k]=W1[k][nn] (128x128),
// W2T[h][k]=W2[k][h] (64x128). grid = 288 blocks x 256.
__global__ __launch_bounds__(256) void prep_weights(
    const float* __restrict__ w1a, const float* __restrict__ w1b,
    const float* __restrict__ w1c, const float* __restrict__ w2a,
    const float* __restrict__ w2b, const float* __restrict__ w2c,
    ushort_t* __restrict__ o1a, ushort_t* __restrict__ o1b,
    ushort_t* __restrict__ o1c, ushort_t* __restrict__ o2a,
    ushort_t* __restrict__ o2b, ushort_t* __restrict__ o2c) {
  int i = blockIdx.x * 256 + threadIdx.x;
  if (i < 49152) {  // 3 x 128x128
    int a = i >> 14, j = i & 16383;
    int nn = j >> 7, k = j & 127;
    const float* s = (a == 0) ? w1a : (a == 1) ? w1b : w1c;
    ushort_t* d = (a == 0) ? o1a : (a == 1) ? o1b : o1c;
    d[j] = f2bf(s[k * 128 + nn]);
  } else if (i < 73728) {  // 3 x 64x128
    int i2 = i - 49152;
    int a = i2 >> 13, j = i2 & 8191;
    int h = j >> 7, k = j & 127;
    const float* s = (a == 0) ? w2a : (a == 1) ? w2b : w2c;
    ushort_t* d = (a == 0) ? o2a : (a == 1) ? o2b : o2c;
    d[j] = f2bf(s[k * 64 + h]);
  }
}

// ---------------- merged CSR build (both graphs) ----------------

// counts: cnt[rS[i]] for i<e (sadj), cnt[n + rF[i-e]] for i>=e (fadj)
__global__ __launch_bounds__(256) void hist2_kernel(
    const int* __restrict__ rowS, const int* __restrict__ rowF,
    int* __restrict__ cnt, int n, int e) {
  int i = blockIdx.x * 256 + threadIdx.x;
  if (i < e)
    atomicAdd(&cnt[rowS[i]], 1);
  else if (i < 2 * e)
    atomicAdd(&cnt[n + rowF[i - e]], 1);
}

__global__ __launch_bounds__(256) void scan_partial(
    const int* __restrict__ cnt, int* __restrict__ part, int total) {
  __shared__ int red[256];
  int t = threadIdx.x;
  int base = blockIdx.x * 1024 + t * 4;
  int s = 0;
#pragma unroll
  for (int j = 0; j < 4; ++j) {
    int idx = base + j;
    if (idx < total) s += cnt[idx];
  }
  red[t] = s;
  __syncthreads();
#pragma unroll
  for (int d = 128; d > 0; d >>= 1) {
    if (t < d) red[t] += red[t + d];
    __syncthreads();
  }
  if (t == 0) part[blockIdx.x] = red[0];
}

__global__ __launch_bounds__(256) void scan_tops(int* __restrict__ part,
                                                 int nb) {
  __shared__ int lds[256];
  int t = threadIdx.x;
  lds[t] = (t < nb) ? part[t] : 0;
  __syncthreads();
#pragma unroll
  for (int d = 1; d < 256; d <<= 1) {
    int v = (t >= d) ? lds[t - d] : 0;
    __syncthreads();
    lds[t] += v;
    __syncthreads();
  }
  if (t < nb) part[t] = (t == 0) ? 0 : lds[t - 1];
}

// writes rowptr[0..total) + woff; rowptr[total] = tail (=2e)
__global__ __launch_bounds__(256) void scan_final(
    const int* __restrict__ cnt, const int* __restrict__ part,
    int* __restrict__ rowptr, int* __restrict__ woff, int total, int tail) {
  __shared__ int lds[256];
  int t = threadIdx.x;
  int base = blockIdx.x * 1024 + t * 4;
  int c[4];
  int s = 0;
#pragma unroll
  for (int j = 0; j < 4; ++j) {
    int idx = base + j;
    c[j] = (idx < total) ? cnt[idx] : 0;
    s += c[j];
  }
  lds[t] = s;
  __syncthreads();
#pragma unroll
  for (int d = 1; d < 256; d <<= 1) {
    int v = (t >= d) ? lds[t - d] : 0;
    __syncthreads();
    lds[t] += v;
    __syncthreads();
  }
  int off = part[blockIdx.x] + ((t == 0) ? 0 : lds[t - 1]);
#pragma unroll
  for (int j = 0; j < 4; ++j) {
    int idx = base + j;
    if (idx < total) {
      rowptr[idx] = off;
      woff[idx] = off;
      off += c[j];
    }
  }
  if (blockIdx.x == 0 && t == 0) rowptr[total] = tail;
}

// single packed scatter for both graphs: packed[p] = (col, val_bits)
__global__ __launch_bounds__(256) void scatter2_kernel(
    const int* __restrict__ rowS, const int* __restrict__ colS,
    const float* __restrict__ valS, const int* __restrict__ rowF,
    const int* __restrict__ colF, const float* __restrict__ valF,
    int* __restrict__ woff, int2* __restrict__ packed, int n, int e) {
  int i = blockIdx.x * 256 + threadIdx.x;
  int bucket, c;
  float v;
  if (i < e) {
    bucket = rowS[i];
    c = colS[i];
    v = valS[i];
  } else if (i < 2 * e) {
    bucket = n + rowF[i - e];
    c = colF[i - e];
    v = valF[i - e];
  } else {
    return;
  }
  int p = atomicAdd(&woff[bucket], 1);
  packed[p] = make_int2(c, __float_as_int(v));
}

// ---------------- CSR SpMM (bf16 gather, fp32 accumulate) ----------------

// 128 feats: 32 lanes/row, bf16 gather, edge-unroll x4; OUTPUT = bf16 [n][128].
__global__ __launch_bounds__(256) void spmm_csr_128(
    const int* __restrict__ rowptr, const int2* __restrict__ packed,
    const ushort_t* __restrict__ h, ushort_t* __restrict__ Ax, int n) {
  int tid = threadIdx.x;
  int r = blockIdx.x * 8 + (tid >> 5);
  if (r >= n) return;
  int lane = tid & 31;
  int lo = rowptr[r], hi = rowptr[r + 1];
  const ushort4* h4 = (const ushort4*)h;  // row stride = 32 ushort4
  float4 acc = make_float4(0.f, 0.f, 0.f, 0.f);
  int e = lo;
  for (; e + 4 <= hi; e += 4) {
    int2 p0 = packed[e], p1 = packed[e + 1], p2 = packed[e + 2],
         p3 = packed[e + 3];
    float v0 = __int_as_float(p0.y), v1 = __int_as_float(p1.y),
          v2 = __int_as_float(p2.y), v3 = __int_as_float(p3.y);
    ushort4 q0 = h4[(long)p0.x * 32 + lane];
    ushort4 q1 = h4[(long)p1.x * 32 + lane];
    ushort4 q2 = h4[(long)p2.x * 32 + lane];
    ushort4 q3 = h4[(long)p3.x * 32 + lane];
    acc.x += v0 * bf2f(q0.x) + v1 * bf2f(q1.x) + v2 * bf2f(q2.x) + v3 * bf2f(q3.x);
    acc.y += v0 * bf2f(q0.y) + v1 * bf2f(q1.y) + v2 * bf2f(q2.y) + v3 * bf2f(q3.y);
    acc.z += v0 * bf2f(q0.z) + v1 * bf2f(q1.z) + v2 * bf2f(q2.z) + v3 * bf2f(q3.z);
    acc.w += v0 * bf2f(q0.w) + v1 * bf2f(q1.w) + v2 * bf2f(q2.w) + v3 * bf2f(q3.w);
  }
  for (; e < hi; ++e) {
    int2 p = packed[e];
    float v = __int_as_float(p.y);
    ushort4 q = h4[(long)p.x * 32 + lane];
    acc.x += v * bf2f(q.x);
    acc.y += v * bf2f(q.y);
    acc.z += v * bf2f(q.z);
    acc.w += v * bf2f(q.w);
  }
  ushort4 o;
  o.x = f2bf(acc.x);
  o.y = f2bf(acc.y);
  o.z = f2bf(acc.z);
  o.w = f2bf(acc.w);
  ((ushort4*)Ax)[(long)r * 32 + lane] = o;
}

// Dual 64-feat SpMM, bf16 gather: lanes 0-15 -> hS/outS(+bS), 16-31 -> hC.
__global__ __launch_bounds__(256) void spmm_dual64(
    const int* __restrict__ rowptr, const int2* __restrict__ packed,
    const ushort_t* __restrict__ hS, const ushort_t* __restrict__ hC,
    const float* __restrict__ bS, const float* __restrict__ bC,
    float* __restrict__ outS, float* __restrict__ outC, int n) {
  int tid = threadIdx.x;
  int r = blockIdx.x * 8 + (tid >> 5);
  if (r >= n) return;
  int lane = tid & 31;
  int half = lane >> 4;
  int li = lane & 15;
  const ushort4* h4 = (const ushort4*)(half ? hC : hS);  // row = 16 ushort4
  float4 acc = ((const float4*)(half ? bC : bS))[li];
  int lo = rowptr[r], hi = rowptr[r + 1];
  int e = lo;
  for (; e + 4 <= hi; e += 4) {
    int2 p0 = packed[e], p1 = packed[e + 1], p2 = packed[e + 2],
         p3 = packed[e + 3];
    float v0 = __int_as_float(p0.y), v1 = __int_as_float(p1.y),
          v2 = __int_as_float(p2.y), v3 = __int_as_float(p3.y);
    ushort4 q0 = h4[(long)p0.x * 16 + li];
    ushort4 q1 = h4[(long)p1.x * 16 + li];
    ushort4 q2 = h4[(long)p2.x * 16 + li];
    ushort4 q3 = h4[(long)p3.x * 16 + li];
    acc.x += v0 * bf2f(q0.x) + v1 * bf2f(q1.x) + v2 * bf2f(q2.x) + v3 * bf2f(q3.x);
    acc.y += v0 * bf2f(q0.y) + v1 * bf2f(q1.y) + v2 * bf2f(q2.y) + v3 * bf2f(q3.y);
    acc.z += v0 * bf2f(q0.z) + v1 * bf2f(q1.z) + v2 * bf2f(q2.z) + v3 * bf2f(q3.z);
    acc.w += v0 * bf2f(q0.w) + v1 * bf2f(q1.w) + v2 * bf2f(q2.w) + v3 * bf2f(q3.w);
  }
  for (; e < hi; ++e) {
    int2 p = packed[e];
    float v = __int_as_float(p.y);
    ushort4 q = h4[(long)p.x * 16 + li];
    acc.x += v * bf2f(q.x);
    acc.y += v * bf2f(q.y);
    acc.z += v * bf2f(q.z);
    acc.w += v * bf2f(q.w);
  }
  float4* o = (float4*)(half ? outC : outS);
  o[(long)r * 16 + li] = acc;
}

// ---------------- fused dense chain, bf16 MFMA (known-good) ----------------
__global__ __launch_bounds__(256) void fused_l1l2_mfma(
    const ushort_t* __restrict__ Ax,   // [n][128] bf16
    const ushort_t* __restrict__ W1T,  // [128][128] bf16
    const float* __restrict__ B1,      // [128] f32
    const ushort_t* __restrict__ W2T,  // [64][128] bf16
    ushort_t* __restrict__ H,          // [n][64] bf16
    int n) {
  __shared__ __attribute__((aligned(16))) ushort_t sp[64][136];  // S' (+pad)
  int tid = threadIdx.x;
  int w = tid >> 6;
  int l = tid & 63;
  int lo16 = l & 15;
  int g = l >> 4;
  long node0 = (long)blockIdx.x * 64;

  // ---- GEMM1 (flipped): S^T = W1T x Ax^T ----
  f32x4 acc1[2][4];
#pragma unroll
  for (int m = 0; m < 2; ++m)
#pragma unroll
    for (int nu = 0; nu < 4; ++nu) acc1[m][nu] = (f32x4){0.f, 0.f, 0.f, 0.f};

#pragma unroll 1
  for (int t = 0; t < 4; ++t) {
    short8 af0 = *(const short8*)(W1T + (32 * w + lo16) * 128 + 32 * t + 8 * g);
    short8 af1 =
        *(const short8*)(W1T + (32 * w + 16 + lo16) * 128 + 32 * t + 8 * g);
#pragma unroll
    for (int nu = 0; nu < 4; ++nu) {
      long node = node0 + 16 * nu + lo16;
      if (node > (long)n - 1) node = (long)n - 1;
      short8 bf = *(const short8*)(Ax + node * 128 + 32 * t + 8 * g);
      acc1[0][nu] =
          __builtin_amdgcn_mfma_f32_16x16x32_bf16(af0, bf, acc1[0][nu], 0, 0, 0);
      acc1[1][nu] =
          __builtin_amdgcn_mfma_f32_16x16x32_bf16(af1, bf, acc1[1][nu], 0, 0, 0);
    }
  }

  // relu + bias, pack 4 contiguous sfeats -> S' LDS
#pragma unroll
  for (int m = 0; m < 2; ++m) {
    int sf = 32 * w + 16 * m + 4 * g;
    float4 b1v = *(const float4*)(B1 + sf);
#pragma unroll
    for (int nu = 0; nu < 4; ++nu) {
      int node_l = 16 * nu + lo16;
      ushort4 pk;
      pk.x = f2bf(fmaxf(acc1[m][nu][0] + b1v.x, 0.f));
      pk.y = f2bf(fmaxf(acc1[m][nu][1] + b1v.y, 0.f));
      pk.z = f2bf(fmaxf(acc1[m][nu][2] + b1v.z, 0.f));
      pk.w = f2bf(fmaxf(acc1[m][nu][3] + b1v.w, 0.f));
      *(ushort4*)(&sp[node_l][sf]) = pk;
    }
  }
  __syncthreads();

  // ---- GEMM2 (standard): H = S' @ W2 ----
  f32x4 acc2[4];
#pragma unroll
  for (int nu = 0; nu < 4; ++nu) acc2[nu] = (f32x4){0.f, 0.f, 0.f, 0.f};
#pragma unroll 1
  for (int t = 0; t < 4; ++t) {
    short8 af = *(const short8*)(&sp[16 * w + lo16][32 * t + 8 * g]);
#pragma unroll
    for (int nu = 0; nu < 4; ++nu) {
      short8 bf =
          *(const short8*)(W2T + (16 * nu + lo16) * 128 + 32 * t + 8 * g);
      acc2[nu] =
          __builtin_amdgcn_mfma_f32_16x16x32_bf16(af, bf, acc2[nu], 0, 0, 0);
    }
  }
#pragma unroll
  for (int nu = 0; nu < 4; ++nu) {
#pragma unroll
    for (int r = 0; r < 4; ++r) {
      long node = node0 + 16 * w + 4 * g + r;
      if (node < n) H[node * 64 + 16 * nu + lo16] = f2bf(acc2[nu][r]);
    }
  }
}

// ---------------- final fuse (16 lanes per node) ----------------
__global__ __launch_bounds__(256) void final_fuse(
    const float* __restrict__ emb1, const float* __restrict__ emb2,
    const float* __restrict__ com1, const float* __restrict__ com2,
    const float* __restrict__ attw1, const float* __restrict__ attb1,
    const float* __restrict__ attw2, const float* __restrict__ mlpw,
    const float* __restrict__ mlpb, float* __restrict__ out_logp,
    float* __restrict__ out_beta, float* __restrict__ out_emb, int n) {
  __shared__ __attribute__((aligned(16))) float w1t[16][64];
  __shared__ __attribute__((aligned(16))) float mwt[8][64];
  __shared__ float b1s[16];
  __shared__ float w2s[16];
  __shared__ float mbs[8];
  int tid = threadIdx.x;
  for (int idx = tid; idx < 1024; idx += 256)
    w1t[idx & 15][idx >> 4] = attw1[idx];
  for (int idx = tid; idx < 512; idx += 256)
    mwt[idx & 7][idx >> 3] = mlpw[idx];
  if (tid < 16) {
    b1s[tid] = attb1[tid];
    w2s[tid] = attw2[tid];
  }
  if (tid < 8) mbs[tid] = mlpb[tid];
  __syncthreads();

  int lane = tid & 15;
  long i = ((long)blockIdx.x * 256 + tid) >> 4;
  bool alive = i < n;
  long ii = alive ? i : (long)(n - 1);

  float4 z0 = ((const float4*)emb1)[ii * 16 + lane];
  float4 z1 = ((const float4*)emb2)[ii * 16 + lane];
  float4 x1 = ((const float4*)com1)[ii * 16 + lane];
  float4 x2 = ((const float4*)com2)[ii * 16 + lane];
  float4 z2 = make_float4(0.5f * (x1.x + x2.x), 0.5f * (x1.y + x2.y),
                          0.5f * (x1.z + x2.z), 0.5f * (x1.w + x2.w));

  float a0[16], a1[16], a2[16];
#pragma unroll
  for (int m = 0; m < 16; ++m) {
    float4 w = *(const float4*)&w1t[m][lane * 4];
    a0[m] = z0.x * w.x + z0.y * w.y + z0.z * w.z + z0.w * w.w;
    a1[m] = z1.x * w.x + z1.y * w.y + z1.z * w.z + z1.w * w.w;
    a2[m] = z2.x * w.x + z2.y * w.y + z2.z * w.z + z2.w * w.w;
  }
#pragma unroll
  for (int d = 1; d < 16; d <<= 1) {
#pragma unroll
    for (int m = 0; m < 16; ++m) {
      a0[m] += __shfl_xor(a0[m], d);
      a1[m] += __shfl_xor(a1[m], d);
      a2[m] += __shfl_xor(a2[m], d);
    }
  }
  float sc0 = 0.f, sc1 = 0.f, sc2 = 0.f;
#pragma unroll
  for (int m = 0; m < 16; ++m) {
    float wm = w2s[m], bm = b1s[m];
    sc0 += tanhf(a0[m] + bm) * wm;
    sc1 += tanhf(a1[m] + bm) * wm;
    sc2 += tanhf(a2[m] + bm) * wm;
  }
  float mx = fmaxf(sc0, fmaxf(sc1, sc2));
  float ex0 = expf(sc0 - mx), ex1 = expf(sc1 - mx), ex2 = expf(sc2 - mx);
  float inv = 1.f / (ex0 + ex1 + ex2);
  float be0 = ex0 * inv, be1 = ex1 * inv, be2 = ex2 * inv;

  float4 em;
  em.x = be0 * z0.x + be1 * z1.x + be2 * z2.x;
  em.y = be0 * z0.y + be1 * z1.y + be2 * z2.y;
  em.z = be0 * z0.z + be1 * z1.z + be2 * z2.z;
  em.w = be0 * z0.w + be1 * z1.w + be2 * z2.w;
  if (alive) ((float4*)out_emb)[i * 16 + lane] = em;

  float lg[8];
#pragma unroll
  for (int p = 0; p < 8; ++p) {
    float4 w = *(const float4*)&mwt[p][lane * 4];
    lg[p] = em.x * w.x + em.y * w.y + em.z * w.z + em.w * w.w;
  }
#pragma unroll
  for (int d = 1; d < 16; d <<= 1) {
#pragma unroll
    for (int p = 0; p < 8; ++p) lg[p] += __shfl_xor(lg[p], d);
  }
#pragma unroll
  for (int p = 0; p < 8; ++p) lg[p] += mbs[p];
  float m2 = lg[0];
#pragma unroll
  for (int p = 1; p < 8; ++p) m2 = fmaxf(m2, lg[p]);
  float ssum = 0.f;
#pragma unroll
  for (int p = 0; p < 8; ++p) ssum += expf(lg[p] - m2);
  float ls = m2 + logf(ssum);

  if (alive && lane == 0) {
    float4 o0 = make_float4(lg[0] - ls, lg[1] - ls, lg[2] - ls, lg[3] - ls);
    float4 o1 = make_float4(lg[4] - ls, lg[5] - ls, lg[6] - ls, lg[7] - ls);
    *(float4*)&out_logp[i * 8] = o0;
    *(float4*)&out_logp[i * 8 + 4] = o1;
    out_beta[i * 3 + 0] = be0;
    out_beta[i * 3 + 1] = be1;
    out_beta[i * 3 + 2] = be2;
  }
}

extern "C" void kernel_launch(void* const* d_in, const int* in_sizes, int n_in,
                              void* d_out, int out_size, void* d_ws,
                              size_t ws_size, hipStream_t stream) {
  const float* x = (const float*)d_in[0];
  const int* srow = (const int*)d_in[1];
  const int* scol_in = (const int*)d_in[2];
  const float* sval_in = (const float*)d_in[3];
  const int* frow = (const int*)d_in[4];
  const int* fcol_in = (const int*)d_in[5];
  const float* fval_in = (const float*)d_in[6];
  const float* w_s1_1 = (const float*)d_in[7];
  const float* b_s1_1 = (const float*)d_in[8];
  const float* w_s1_2 = (const float*)d_in[9];
  const float* b_s1_2 = (const float*)d_in[10];
  const float* w_s2_1 = (const float*)d_in[11];
  const float* b_s2_1 = (const float*)d_in[12];
  const float* w_s2_2 = (const float*)d_in[13];
  const float* b_s2_2 = (const float*)d_in[14];
  const float* w_c_1 = (const float*)d_in[15];
  const float* b_c_1 = (const float*)d_in[16];
  const float* w_c_2 = (const float*)d_in[17];
  const float* b_c_2 = (const float*)d_in[18];
  const float* attw1 = (const float*)d_in[19];
  const float* attb1 = (const float*)d_in[20];
  const float* attw2 = (const float*)d_in[21];
  const float* mlpw = (const float*)d_in[22];
  const float* mlpb = (const float*)d_in[23];

  const int n = in_sizes[0] / 128;  // 100000
  const int e = in_sizes[1];        // 1600000

  float* out = (float*)d_out;
  float* o_logp = out;
  float* o_beta = out + (size_t)n * 8;
  float* o_emb1 = out + (size_t)n * 11;
  float* o_com1 = o_emb1 + (size_t)n * 64;
  float* o_com2 = o_com1 + (size_t)n * 64;
  float* o_emb2 = o_com2 + (size_t)n * 64;
  float* o_emb = o_emb2 + (size_t)n * 64;

  // x_bf16 (n*128 bf16 = 25.6MB) in the o_emb region (exact fit);
  // final_fuse overwrites it at the very end.
  ushort_t* x_bf16 = (ushort_t*)o_emb;

  // workspace layout (~80MB, within proven 102.4MB budget)
  ushort_t* ax = (ushort_t*)d_ws;                 // n*128 bf16
  ushort_t* hwS = ax + (size_t)n * 128;           // n*64 bf16
  ushort_t* hwC = hwS + (size_t)n * 64;           // n*64 bf16
  ushort_t* w1t_s1 = hwC + (size_t)n * 64;        // 128*128 bf16
  ushort_t* w1t_s2 = w1t_s1 + 16384;
  ushort_t* w1t_c = w1t_s2 + 16384;
  ushort_t* w2t_s1 = w1t_c + 16384;               // 64*128 bf16
  ushort_t* w2t_s2 = w2t_s1 + 8192;
  ushort_t* w2t_c = w2t_s2 + 8192;
  int* cnt = (int*)(w2t_c + 8192);                // 2n
  int* rowptr = cnt + 2 * n;                      // 2n+1
  int* woff = rowptr + 2 * n + 1;                 // 2n
  int* part = woff + 2 * n;                       // <=256
  int2* packed = (int2*)(part + 256);             // 2e int2 (25.6MB)

  const int histBlocks2 = (2 * e + 255) / 256;
  const int scanBlocks2 = (2 * n + 1023) / 1024;  // 196
  const int spmmBlocks = (n + 7) / 8;
  const int cvtBlocks = (int)(((long)n * 32 + 255) / 256);
  const int mfmaBlocks = (n + 63) / 64;

  // one-time preprocessing
  cvt_bf16<<<cvtBlocks, 256, 0, stream>>>(x, x_bf16, (long)n * 32);
  prep_weights<<<288, 256, 0, stream>>>(w_s1_1, w_s2_1, w_c_1, w_s1_2, w_s2_2,
                                        w_c_2, w1t_s1, w1t_s2, w1t_c, w2t_s1,
                                        w2t_s2, w2t_c);

  // merged CSR build: both graphs in one pass
  hipMemsetAsync(cnt, 0, (size_t)(2 * n) * sizeof(int), stream);
  hist2_kernel<<<histBlocks2, 256, 0, stream>>>(srow, frow, cnt, n, e);
  scan_partial<<<scanBlocks2, 256, 0, stream>>>(cnt, part, 2 * n);
  scan_tops<<<1, 256, 0, stream>>>(part, scanBlocks2);
  scan_final<<<scanBlocks2, 256, 0, stream>>>(cnt, part, rowptr, woff, 2 * n,
                                              2 * e);
  scatter2_kernel<<<histBlocks2, 256, 0, stream>>>(
      srow, scol_in, sval_in, frow, fcol_in, fval_in, woff, packed, n, e);

  const int* rowptrS = rowptr;      // sadj rows: rowptr[0..n]
  const int* rowptrF = rowptr + n;  // fadj rows: rowptr[n..2n]

  // --- graph sadj: emb1 (w_s1) + com1 (w_c) ---
  spmm_csr_128<<<spmmBlocks, 256, 0, stream>>>(rowptrS, packed, x_bf16, ax, n);
  fused_l1l2_mfma<<<mfmaBlocks, 256, 0, stream>>>(ax, w1t_s1, b_s1_1, w2t_s1,
                                                  hwS, n);
  fused_l1l2_mfma<<<mfmaBlocks, 256, 0, stream>>>(ax, w1t_c, b_c_1, w2t_c,
                                                  hwC, n);
  spmm_dual64<<<spmmBlocks, 256, 0, stream>>>(rowptrS, packed, hwS, hwC,
                                              b_s1_2, b_c_2, o_emb1, o_com1,
                                              n);

  // --- graph fadj: com2 (w_c) + emb2 (w_s2) ---
  spmm_csr_128<<<spmmBlocks, 256, 0, stream>>>(rowptrF, packed, x_bf16, ax, n);
  fused_l1l2_mfma<<<mfmaBlocks, 256, 0, stream>>>(ax, w1t_s2, b_s2_1, w2t_s2,
                                                  hwS, n);
  fused_l1l2_mfma<<<mfmaBlocks, 256, 0, stream>>>(ax, w1t_c, b_c_1, w2t_c,
                                                  hwC, n);
  spmm_dual64<<<spmmBlocks, 256, 0, stream>>>(rowptrF, packed, hwS, hwC,
                                              b_s2_2, b_c_2, o_emb2, o_com2,
                                              n);

  final_fuse<<<(int)(((long)n * 16 + 255) / 256), 256, 0, stream>>>(
      o_emb1, o_emb2, o_com1, o_com2, attw1, attb1, attw2, mlpw, mlpb, o_logp,
      o_beta, o_emb, n);
}

// Round 12
// 638.239 us; speedup vs baseline: 7.4491x; 1.3373x over previous
//
#include <hip/hip_runtime.h>

// ---------------------------------------------------------------------------
// SFGCN forward on MI355X, round 12:
//  - CSR build via TWO-LEVEL COUNTING SORT (no random 8B scatters):
//    coarse_hist (LDS-aggregated) -> coarse_scan (782 buckets of 256 vrows)
//    -> coarse_scatter (per-block reservations; contiguous runs per bucket)
//    -> fine_sort (1 block/bucket: 256-row LDS hist+scan emits rowptr AND
//    scatters within an L2-resident 32KB window). Replaces the 330us
//    hist2/scan/scatter2 chain whose 3.2M random line-touches cost 223MB HBM.
//  - SpMM (bf16 gather), MFMA dense chain, final_fuse unchanged.
// ---------------------------------------------------------------------------

typedef unsigned short ushort_t;
typedef float f32x4 __attribute__((ext_vector_type(4)));
typedef short short8 __attribute__((ext_vector_type(8)));

#define NBLK1 512  // blocks for coarse hist/scatter (grid-stride)

__device__ __forceinline__ ushort_t f2bf(float f) {  // round-to-nearest-even
  unsigned u = __float_as_uint(f);
  unsigned r = (u + 0x7FFFu + ((u >> 16) & 1u)) >> 16;
  return (ushort_t)r;
}
__device__ __forceinline__ float bf2f(ushort_t b) {
  return __uint_as_float((unsigned)b << 16);
}

// total4 float4 chunks -> ushort4 bf16 chunks
__global__ __launch_bounds__(256) void cvt_bf16(
    const float* __restrict__ in, ushort_t* __restrict__ out, long total4) {
  long i = (long)blockIdx.x * 256 + threadIdx.x;
  if (i >= total4) return;
  float4 v = ((const float4*)in)[i];
  ushort4 o;
  o.x = f2bf(v.x);
  o.y = f2bf(v.y);
  o.z = f2bf(v.z);
  o.w = f2bf(v.w);
  ((ushort4*)out)[i] = o;
}

// Transpose+cast the 3 weight pairs to bf16.
__global__ __launch_bounds__(256) void prep_weights(
    const float* __restrict__ w1a, const float* __restrict__ w1b,
    const float* __restrict__ w1c, const float* __restrict__ w2a,
    const float* __restrict__ w2b, const float* __restrict__ w2c,
    ushort_t* __restrict__ o1a, ushort_t* __restrict__ o1b,
    ushort_t* __restrict__ o1c, ushort_t* __restrict__ o2a,
    ushort_t* __restrict__ o2b, ushort_t* __restrict__ o2c) {
  int i = blockIdx.x * 256 + threadIdx.x;
  if (i < 49152) {  // 3 x 128x128
    int a = i >> 14, j = i & 16383;
    int nn = j >> 7, k = j & 127;
    const float* s = (a == 0) ? w1a : (a == 1) ? w1b : w1c;
    ushort_t* d = (a == 0) ? o1a : (a == 1) ? o1b : o1c;
    d[j] = f2bf(s[k * 128 + nn]);
  } else if (i < 73728) {  // 3 x 64x128
    int i2 = i - 49152;
    int a = i2 >> 13, j = i2 & 8191;
    int h = j >> 7, k = j & 127;
    const float* s = (a == 0) ? w2a : (a == 1) ? w2b : w2c;
    ushort_t* d = (a == 0) ? o2a : (a == 1) ? o2b : o2c;
    d[j] = f2bf(s[k * 64 + h]);
  }
}

// ---------------- two-level counting sort CSR build ----------------
// vrow = row (sadj) or n+row (fadj), in [0, 2n). bucket = vrow>>8.

__global__ __launch_bounds__(256) void coarse_hist(
    const int* __restrict__ rowS, const int* __restrict__ rowF,
    int* __restrict__ bkt_cnt, int n, int e, int nb) {
  __shared__ int lh[800];
  int t = threadIdx.x;
  for (int j = t; j < nb; j += 256) lh[j] = 0;
  __syncthreads();
  long total = 2L * e;
  long stride = (long)NBLK1 * 256;
  for (long i = (long)blockIdx.x * 256 + t; i < total; i += stride) {
    int vrow = (i < e) ? rowS[i] : (n + rowF[i - e]);
    atomicAdd(&lh[vrow >> 8], 1);
  }
  __syncthreads();
  for (int j = t; j < nb; j += 256)
    if (lh[j]) atomicAdd(&bkt_cnt[j], lh[j]);
}

// single-block exclusive scan over nb (<=1024) counts; off[nb] = total.
__global__ __launch_bounds__(256) void coarse_scan(
    const int* __restrict__ cnt, int* __restrict__ off, int nb, int total) {
  __shared__ int lds[256];
  int t = threadIdx.x;
  int c[4];
  int s = 0;
#pragma unroll
  for (int j = 0; j < 4; ++j) {
    int idx = t * 4 + j;
    c[j] = (idx < nb) ? cnt[idx] : 0;
    s += c[j];
  }
  lds[t] = s;
  __syncthreads();
#pragma unroll
  for (int d = 1; d < 256; d <<= 1) {
    int v = (t >= d) ? lds[t - d] : 0;
    __syncthreads();
    lds[t] += v;
    __syncthreads();
  }
  int o = (t == 0) ? 0 : lds[t - 1];
#pragma unroll
  for (int j = 0; j < 4; ++j) {
    int idx = t * 4 + j;
    if (idx < nb) off[idx] = o;
    o += c[j];
  }
  if (t == 0) off[nb] = total;
}

// scatter edges into coarse buckets. Per block: LDS hist of its edge slice,
// ONE reservation atomic per touched bucket, then LDS-ranked placement ->
// each block writes contiguous runs (~25 edges) per bucket.
// tmp[p] = (col | vlow<<24, val_bits); col < 2^24, vlow = vrow & 255.
__global__ __launch_bounds__(256) void coarse_scatter(
    const int* __restrict__ rowS, const int* __restrict__ colS,
    const float* __restrict__ valS, const int* __restrict__ rowF,
    const int* __restrict__ colF, const float* __restrict__ valF,
    const int* __restrict__ bkt_off, int* __restrict__ bkt_woff,
    int2* __restrict__ tmp, int n, int e, int nb) {
  __shared__ int lh[800];
  __shared__ int lb[800];
  __shared__ int gb[800];
  int t = threadIdx.x;
  for (int j = t; j < nb; j += 256) {
    lh[j] = 0;
    lb[j] = 0;
  }
  __syncthreads();
  long total = 2L * e;
  long stride = (long)NBLK1 * 256;
  for (long i = (long)blockIdx.x * 256 + t; i < total; i += stride) {
    int vrow = (i < e) ? rowS[i] : (n + rowF[i - e]);
    atomicAdd(&lh[vrow >> 8], 1);
  }
  __syncthreads();
  for (int j = t; j < nb; j += 256) {
    int h = lh[j];
    gb[j] = h ? (bkt_off[j] + atomicAdd(&bkt_woff[j], h)) : 0;
  }
  __syncthreads();
  for (long i = (long)blockIdx.x * 256 + t; i < total; i += stride) {
    int vrow, c;
    float v;
    if (i < e) {
      vrow = rowS[i];
      c = colS[i];
      v = valS[i];
    } else {
      vrow = n + rowF[i - e];
      c = colF[i - e];
      v = valF[i - e];
    }
    int b = vrow >> 8;
    int k = atomicAdd(&lb[b], 1);
    tmp[gb[b] + k] = make_int2(c | ((vrow & 255) << 24), __float_as_int(v));
  }
}

// one block per coarse bucket: 256-row LDS hist + scan -> rowptr, then
// in-bucket scatter to final packed (L2-resident ~32KB window).
__global__ __launch_bounds__(256) void fine_sort(
    const int* __restrict__ bkt_off, const int2* __restrict__ tmp,
    int2* __restrict__ packed, int* __restrict__ rowptr, int vtotal,
    int etotal) {
  __shared__ int hist[256];
  __shared__ int scn[256];
  __shared__ int rowb[256];
  __shared__ int bump[256];
  int b = blockIdx.x;
  int t = threadIdx.x;
  int lo = bkt_off[b], hi = bkt_off[b + 1];
  hist[t] = 0;
  bump[t] = 0;
  __syncthreads();
  for (int i = lo + t; i < hi; i += 256)
    atomicAdd(&hist[((unsigned)tmp[i].x) >> 24], 1);
  __syncthreads();
  scn[t] = hist[t];
  __syncthreads();
#pragma unroll
  for (int d = 1; d < 256; d <<= 1) {
    int v = (t >= d) ? scn[t - d] : 0;
    __syncthreads();
    scn[t] += v;
    __syncthreads();
  }
  int rb = lo + ((t == 0) ? 0 : scn[t - 1]);
  rowb[t] = rb;
  int vrow = b * 256 + t;
  if (vrow < vtotal) rowptr[vrow] = rb;
  __syncthreads();
  for (int i = lo + t; i < hi; i += 256) {
    int2 p = tmp[i];
    int vl = ((unsigned)p.x) >> 24;
    int dest = rowb[vl] + atomicAdd(&bump[vl], 1);
    packed[dest] = make_int2(p.x & 0xFFFFFF, p.y);
  }
  if (b == 0 && t == 0) rowptr[vtotal] = etotal;
}

// ---------------- CSR SpMM (bf16 gather, fp32 accumulate) ----------------

__global__ __launch_bounds__(256) void spmm_csr_128(
    const int* __restrict__ rowptr, const int2* __restrict__ packed,
    const ushort_t* __restrict__ h, ushort_t* __restrict__ Ax, int n) {
  int tid = threadIdx.x;
  int r = blockIdx.x * 8 + (tid >> 5);
  if (r >= n) return;
  int lane = tid & 31;
  int lo = rowptr[r], hi = rowptr[r + 1];
  const ushort4* h4 = (const ushort4*)h;  // row stride = 32 ushort4
  float4 acc = make_float4(0.f, 0.f, 0.f, 0.f);
  int e = lo;
  for (; e + 4 <= hi; e += 4) {
    int2 p0 = packed[e], p1 = packed[e + 1], p2 = packed[e + 2],
         p3 = packed[e + 3];
    float v0 = __int_as_float(p0.y), v1 = __int_as_float(p1.y),
          v2 = __int_as_float(p2.y), v3 = __int_as_float(p3.y);
    ushort4 q0 = h4[(long)p0.x * 32 + lane];
    ushort4 q1 = h4[(long)p1.x * 32 + lane];
    ushort4 q2 = h4[(long)p2.x * 32 + lane];
    ushort4 q3 = h4[(long)p3.x * 32 + lane];
    acc.x += v0 * bf2f(q0.x) + v1 * bf2f(q1.x) + v2 * bf2f(q2.x) + v3 * bf2f(q3.x);
    acc.y += v0 * bf2f(q0.y) + v1 * bf2f(q1.y) + v2 * bf2f(q2.y) + v3 * bf2f(q3.y);
    acc.z += v0 * bf2f(q0.z) + v1 * bf2f(q1.z) + v2 * bf2f(q2.z) + v3 * bf2f(q3.z);
    acc.w += v0 * bf2f(q0.w) + v1 * bf2f(q1.w) + v2 * bf2f(q2.w) + v3 * bf2f(q3.w);
  }
  for (; e < hi; ++e) {
    int2 p = packed[e];
    float v = __int_as_float(p.y);
    ushort4 q = h4[(long)p.x * 32 + lane];
    acc.x += v * bf2f(q.x);
    acc.y += v * bf2f(q.y);
    acc.z += v * bf2f(q.z);
    acc.w += v * bf2f(q.w);
  }
  ushort4 o;
  o.x = f2bf(acc.x);
  o.y = f2bf(acc.y);
  o.z = f2bf(acc.z);
  o.w = f2bf(acc.w);
  ((ushort4*)Ax)[(long)r * 32 + lane] = o;
}

__global__ __launch_bounds__(256) void spmm_dual64(
    const int* __restrict__ rowptr, const int2* __restrict__ packed,
    const ushort_t* __restrict__ hS, const ushort_t* __restrict__ hC,
    const float* __restrict__ bS, const float* __restrict__ bC,
    float* __restrict__ outS, float* __restrict__ outC, int n) {
  int tid = threadIdx.x;
  int r = blockIdx.x * 8 + (tid >> 5);
  if (r >= n) return;
  int lane = tid & 31;
  int half = lane >> 4;
  int li = lane & 15;
  const ushort4* h4 = (const ushort4*)(half ? hC : hS);  // row = 16 ushort4
  float4 acc = ((const float4*)(half ? bC : bS))[li];
  int lo = rowptr[r], hi = rowptr[r + 1];
  int e = lo;
  for (; e + 4 <= hi; e += 4) {
    int2 p0 = packed[e], p1 = packed[e + 1], p2 = packed[e + 2],
         p3 = packed[e + 3];
    float v0 = __int_as_float(p0.y), v1 = __int_as_float(p1.y),
          v2 = __int_as_float(p2.y), v3 = __int_as_float(p3.y);
    ushort4 q0 = h4[(long)p0.x * 16 + li];
    ushort4 q1 = h4[(long)p1.x * 16 + li];
    ushort4 q2 = h4[(long)p2.x * 16 + li];
    ushort4 q3 = h4[(long)p3.x * 16 + li];
    acc.x += v0 * bf2f(q0.x) + v1 * bf2f(q1.x) + v2 * bf2f(q2.x) + v3 * bf2f(q3.x);
    acc.y += v0 * bf2f(q0.y) + v1 * bf2f(q1.y) + v2 * bf2f(q2.y) + v3 * bf2f(q3.y);
    acc.z += v0 * bf2f(q0.z) + v1 * bf2f(q1.z) + v2 * bf2f(q2.z) + v3 * bf2f(q3.z);
    acc.w += v0 * bf2f(q0.w) + v1 * bf2f(q1.w) + v2 * bf2f(q2.w) + v3 * bf2f(q3.w);
  }
  for (; e < hi; ++e) {
    int2 p = packed[e];
    float v = __int_as_float(p.y);
    ushort4 q = h4[(long)p.x * 16 + li];
    acc.x += v * bf2f(q.x);
    acc.y += v * bf2f(q.y);
    acc.z += v * bf2f(q.z);
    acc.w += v * bf2f(q.w);
  }
  float4* o = (float4*)(half ? outC : outS);
  o[(long)r * 16 + li] = acc;
}

// ---------------- fused dense chain, bf16 MFMA (known-good) ----------------
__global__ __launch_bounds__(256) void fused_l1l2_mfma(
    const ushort_t* __restrict__ Ax,   // [n][128] bf16
    const ushort_t* __restrict__ W1T,  // [128][128] bf16
    const float* __restrict__ B1,      // [128] f32
    const ushort_t* __restrict__ W2T,  // [64][128] bf16
    ushort_t* __restrict__ H,          // [n][64] bf16
    int n) {
  __shared__ __attribute__((aligned(16))) ushort_t sp[64][136];  // S' (+pad)
  int tid = threadIdx.x;
  int w = tid >> 6;
  int l = tid & 63;
  int lo16 = l & 15;
  int g = l >> 4;
  long node0 = (long)blockIdx.x * 64;

  // ---- GEMM1 (flipped): S^T = W1T x Ax^T ----
  f32x4 acc1[2][4];
#pragma unroll
  for (int m = 0; m < 2; ++m)
#pragma unroll
    for (int nu = 0; nu < 4; ++nu) acc1[m][nu] = (f32x4){0.f, 0.f, 0.f, 0.f};

#pragma unroll 1
  for (int t = 0; t < 4; ++t) {
    short8 af0 = *(const short8*)(W1T + (32 * w + lo16) * 128 + 32 * t + 8 * g);
    short8 af1 =
        *(const short8*)(W1T + (32 * w + 16 + lo16) * 128 + 32 * t + 8 * g);
#pragma unroll
    for (int nu = 0; nu < 4; ++nu) {
      long node = node0 + 16 * nu + lo16;
      if (node > (long)n - 1) node = (long)n - 1;
      short8 bf = *(const short8*)(Ax + node * 128 + 32 * t + 8 * g);
      acc1[0][nu] =
          __builtin_amdgcn_mfma_f32_16x16x32_bf16(af0, bf, acc1[0][nu], 0, 0, 0);
      acc1[1][nu] =
          __builtin_amdgcn_mfma_f32_16x16x32_bf16(af1, bf, acc1[1][nu], 0, 0, 0);
    }
  }

  // relu + bias, pack 4 contiguous sfeats -> S' LDS
#pragma unroll
  for (int m = 0; m < 2; ++m) {
    int sf = 32 * w + 16 * m + 4 * g;
    float4 b1v = *(const float4*)(B1 + sf);
#pragma unroll
    for (int nu = 0; nu < 4; ++nu) {
      int node_l = 16 * nu + lo16;
      ushort4 pk;
      pk.x = f2bf(fmaxf(acc1[m][nu][0] + b1v.x, 0.f));
      pk.y = f2bf(fmaxf(acc1[m][nu][1] + b1v.y, 0.f));
      pk.z = f2bf(fmaxf(acc1[m][nu][2] + b1v.z, 0.f));
      pk.w = f2bf(fmaxf(acc1[m][nu][3] + b1v.w, 0.f));
      *(ushort4*)(&sp[node_l][sf]) = pk;
    }
  }
  __syncthreads();

  // ---- GEMM2 (standard): H = S' @ W2 ----
  f32x4 acc2[4];
#pragma unroll
  for (int nu = 0; nu < 4; ++nu) acc2[nu] = (f32x4){0.f, 0.f, 0.f, 0.f};
#pragma unroll 1
  for (int t = 0; t < 4; ++t) {
    short8 af = *(const short8*)(&sp[16 * w + lo16][32 * t + 8 * g]);
#pragma unroll
    for (int nu = 0; nu < 4; ++nu) {
      short8 bf =
          *(const short8*)(W2T + (16 * nu + lo16) * 128 + 32 * t + 8 * g);
      acc2[nu] =
          __builtin_amdgcn_mfma_f32_16x16x32_bf16(af, bf, acc2[nu], 0, 0, 0);
    }
  }
#pragma unroll
  for (int nu = 0; nu < 4; ++nu) {
#pragma unroll
    for (int r = 0; r < 4; ++r) {
      long node = node0 + 16 * w + 4 * g + r;
      if (node < n) H[node * 64 + 16 * nu + lo16] = f2bf(acc2[nu][r]);
    }
  }
}

// ---------------- final fuse (16 lanes per node) ----------------
__global__ __launch_bounds__(256) void final_fuse(
    const float* __restrict__ emb1, const float* __restrict__ emb2,
    const float* __restrict__ com1, const float* __restrict__ com2,
    const float* __restrict__ attw1, const float* __restrict__ attb1,
    const float* __restrict__ attw2, const float* __restrict__ mlpw,
    const float* __restrict__ mlpb, float* __restrict__ out_logp,
    float* __restrict__ out_beta, float* __restrict__ out_emb, int n) {
  __shared__ __attribute__((aligned(16))) float w1t[16][64];
  __shared__ __attribute__((aligned(16))) float mwt[8][64];
  __shared__ float b1s[16];
  __shared__ float w2s[16];
  __shared__ float mbs[8];
  int tid = threadIdx.x;
  for (int idx = tid; idx < 1024; idx += 256)
    w1t[idx & 15][idx >> 4] = attw1[idx];
  for (int idx = tid; idx < 512; idx += 256)
    mwt[idx & 7][idx >> 3] = mlpw[idx];
  if (tid < 16) {
    b1s[tid] = attb1[tid];
    w2s[tid] = attw2[tid];
  }
  if (tid < 8) mbs[tid] = mlpb[tid];
  __syncthreads();

  int lane = tid & 15;
  long i = ((long)blockIdx.x * 256 + tid) >> 4;
  bool alive = i < n;
  long ii = alive ? i : (long)(n - 1);

  float4 z0 = ((const float4*)emb1)[ii * 16 + lane];
  float4 z1 = ((const float4*)emb2)[ii * 16 + lane];
  float4 x1 = ((const float4*)com1)[ii * 16 + lane];
  float4 x2 = ((const float4*)com2)[ii * 16 + lane];
  float4 z2 = make_float4(0.5f * (x1.x + x2.x), 0.5f * (x1.y + x2.y),
                          0.5f * (x1.z + x2.z), 0.5f * (x1.w + x2.w));

  float a0[16], a1[16], a2[16];
#pragma unroll
  for (int m = 0; m < 16; ++m) {
    float4 w = *(const float4*)&w1t[m][lane * 4];
    a0[m] = z0.x * w.x + z0.y * w.y + z0.z * w.z + z0.w * w.w;
    a1[m] = z1.x * w.x + z1.y * w.y + z1.z * w.z + z1.w * w.w;
    a2[m] = z2.x * w.x + z2.y * w.y + z2.z * w.z + z2.w * w.w;
  }
#pragma unroll
  for (int d = 1; d < 16; d <<= 1) {
#pragma unroll
    for (int m = 0; m < 16; ++m) {
      a0[m] += __shfl_xor(a0[m], d);
      a1[m] += __shfl_xor(a1[m], d);
      a2[m] += __shfl_xor(a2[m], d);
    }
  }
  float sc0 = 0.f, sc1 = 0.f, sc2 = 0.f;
#pragma unroll
  for (int m = 0; m < 16; ++m) {
    float wm = w2s[m], bm = b1s[m];
    sc0 += tanhf(a0[m] + bm) * wm;
    sc1 += tanhf(a1[m] + bm) * wm;
    sc2 += tanhf(a2[m] + bm) * wm;
  }
  float mx = fmaxf(sc0, fmaxf(sc1, sc2));
  float ex0 = expf(sc0 - mx), ex1 = expf(sc1 - mx), ex2 = expf(sc2 - mx);
  float inv = 1.f / (ex0 + ex1 + ex2);
  float be0 = ex0 * inv, be1 = ex1 * inv, be2 = ex2 * inv;

  float4 em;
  em.x = be0 * z0.x + be1 * z1.x + be2 * z2.x;
  em.y = be0 * z0.y + be1 * z1.y + be2 * z2.y;
  em.z = be0 * z0.z + be1 * z1.z + be2 * z2.z;
  em.w = be0 * z0.w + be1 * z1.w + be2 * z2.w;
  if (alive) ((float4*)out_emb)[i * 16 + lane] = em;

  float lg[8];
#pragma unroll
  for (int p = 0; p < 8; ++p) {
    float4 w = *(const float4*)&mwt[p][lane * 4];
    lg[p] = em.x * w.x + em.y * w.y + em.z * w.z + em.w * w.w;
  }
#pragma unroll
  for (int d = 1; d < 16; d <<= 1) {
#pragma unroll
    for (int p = 0; p < 8; ++p) lg[p] += __shfl_xor(lg[p], d);
  }
#pragma unroll
  for (int p = 0; p < 8; ++p) lg[p] += mbs[p];
  float m2 = lg[0];
#pragma unroll
  for (int p = 1; p < 8; ++p) m2 = fmaxf(m2, lg[p]);
  float ssum = 0.f;
#pragma unroll
  for (int p = 0; p < 8; ++p) ssum += expf(lg[p] - m2);
  float ls = m2 + logf(ssum);

  if (alive && lane == 0) {
    float4 o0 = make_float4(lg[0] - ls, lg[1] - ls, lg[2] - ls, lg[3] - ls);
    float4 o1 = make_float4(lg[4] - ls, lg[5] - ls, lg[6] - ls, lg[7] - ls);
    *(float4*)&out_logp[i * 8] = o0;
    *(float4*)&out_logp[i * 8 + 4] = o1;
    out_beta[i * 3 + 0] = be0;
    out_beta[i * 3 + 1] = be1;
    out_beta[i * 3 + 2] = be2;
  }
}

extern "C" void kernel_launch(void* const* d_in, const int* in_sizes, int n_in,
                              void* d_out, int out_size, void* d_ws,
                              size_t ws_size, hipStream_t stream) {
  const float* x = (const float*)d_in[0];
  const int* srow = (const int*)d_in[1];
  const int* scol_in = (const int*)d_in[2];
  const float* sval_in = (const float*)d_in[3];
  const int* frow = (const int*)d_in[4];
  const int* fcol_in = (const int*)d_in[5];
  const float* fval_in = (const float*)d_in[6];
  const float* w_s1_1 = (const float*)d_in[7];
  const float* b_s1_1 = (const float*)d_in[8];
  const float* w_s1_2 = (const float*)d_in[9];
  const float* b_s1_2 = (const float*)d_in[10];
  const float* w_s2_1 = (const float*)d_in[11];
  const float* b_s2_1 = (const float*)d_in[12];
  const float* w_s2_2 = (const float*)d_in[13];
  const float* b_s2_2 = (const float*)d_in[14];
  const float* w_c_1 = (const float*)d_in[15];
  const float* b_c_1 = (const float*)d_in[16];
  const float* w_c_2 = (const float*)d_in[17];
  const float* b_c_2 = (const float*)d_in[18];
  const float* attw1 = (const float*)d_in[19];
  const float* attb1 = (const float*)d_in[20];
  const float* attw2 = (const float*)d_in[21];
  const float* mlpw = (const float*)d_in[22];
  const float* mlpb = (const float*)d_in[23];

  const int n = in_sizes[0] / 128;  // 100000
  const int e = in_sizes[1];        // 1600000
  const int vtotal = 2 * n;
  const int nb = (vtotal + 255) >> 8;  // 782 coarse buckets

  float* out = (float*)d_out;
  float* o_logp = out;
  float* o_beta = out + (size_t)n * 8;
  float* o_emb1 = out + (size_t)n * 11;
  float* o_com1 = o_emb1 + (size_t)n * 64;
  float* o_com2 = o_com1 + (size_t)n * 64;
  float* o_emb2 = o_com2 + (size_t)n * 64;
  float* o_emb = o_emb2 + (size_t)n * 64;

  // x_bf16 in o_emb region (25.6MB, exact fit); overwritten by final_fuse.
  ushort_t* x_bf16 = (ushort_t*)o_emb;
  // tmp (coarse-bucketed edges, 25.6MB) in o_emb1 region: fully consumed by
  // fine_sort BEFORE spmm_dual64 writes o_emb1.
  int2* tmp = (int2*)o_emb1;

  // workspace layout (~78MB)
  ushort_t* ax = (ushort_t*)d_ws;                 // n*128 bf16
  ushort_t* hwS = ax + (size_t)n * 128;           // n*64 bf16
  ushort_t* hwC = hwS + (size_t)n * 64;           // n*64 bf16
  ushort_t* w1t_s1 = hwC + (size_t)n * 64;        // 128*128 bf16
  ushort_t* w1t_s2 = w1t_s1 + 16384;
  ushort_t* w1t_c = w1t_s2 + 16384;
  ushort_t* w2t_s1 = w1t_c + 16384;               // 64*128 bf16
  ushort_t* w2t_s2 = w2t_s1 + 8192;
  ushort_t* w2t_c = w2t_s2 + 8192;
  int* rowptr = (int*)(w2t_c + 8192);             // 2n+1
  int* bkt_cnt = rowptr + vtotal + 1;             // nb
  int* bkt_woff = bkt_cnt + nb;                   // nb
  int* bkt_off = bkt_woff + nb;                   // nb+1
  int* tail = bkt_off + nb + 2;                   // align to 8B for int2
  int2* packed = (int2*)(tail + ((((size_t)(tail)&7) == 0) ? 0 : 1));

  const int spmmBlocks = (n + 7) / 8;
  const int cvtBlocks = (int)(((long)n * 32 + 255) / 256);
  const int mfmaBlocks = (n + 63) / 64;

  // one-time preprocessing
  cvt_bf16<<<cvtBlocks, 256, 0, stream>>>(x, x_bf16, (long)n * 32);
  prep_weights<<<288, 256, 0, stream>>>(w_s1_1, w_s2_1, w_c_1, w_s1_2, w_s2_2,
                                        w_c_2, w1t_s1, w1t_s2, w1t_c, w2t_s1,
                                        w2t_s2, w2t_c);

  // two-level counting-sort CSR build (both graphs at once)
  hipMemsetAsync(bkt_cnt, 0, (size_t)(2 * nb) * sizeof(int), stream);
  coarse_hist<<<NBLK1, 256, 0, stream>>>(srow, frow, bkt_cnt, n, e, nb);
  coarse_scan<<<1, 256, 0, stream>>>(bkt_cnt, bkt_off, nb, 2 * e);
  coarse_scatter<<<NBLK1, 256, 0, stream>>>(srow, scol_in, sval_in, frow,
                                            fcol_in, fval_in, bkt_off,
                                            bkt_woff, tmp, n, e, nb);
  fine_sort<<<nb, 256, 0, stream>>>(bkt_off, tmp, packed, rowptr, vtotal,
                                    2 * e);

  const int* rowptrS = rowptr;      // sadj rows: rowptr[0..n]
  const int* rowptrF = rowptr + n;  // fadj rows: rowptr[n..2n]

  // --- graph sadj: emb1 (w_s1) + com1 (w_c) ---
  spmm_csr_128<<<spmmBlocks, 256, 0, stream>>>(rowptrS, packed, x_bf16, ax, n);
  fused_l1l2_mfma<<<mfmaBlocks, 256, 0, stream>>>(ax, w1t_s1, b_s1_1, w2t_s1,
                                                  hwS, n);
  fused_l1l2_mfma<<<mfmaBlocks, 256, 0, stream>>>(ax, w1t_c, b_c_1, w2t_c,
                                                  hwC, n);
  spmm_dual64<<<spmmBlocks, 256, 0, stream>>>(rowptrS, packed, hwS, hwC,
                                              b_s1_2, b_c_2, o_emb1, o_com1,
                                              n);

  // --- graph fadj: com2 (w_c) + emb2 (w_s2) ---
  spmm_csr_128<<<spmmBlocks, 256, 0, stream>>>(rowptrF, packed, x_bf16, ax, n);
  fused_l1l2_mfma<<<mfmaBlocks, 256, 0, stream>>>(ax, w1t_s2, b_s2_1, w2t_s2,
                                                  hwS, n);
  fused_l1l2_mfma<<<mfmaBlocks, 256, 0, stream>>>(ax, w1t_c, b_c_1, w2t_c,
                                                  hwC, n);
  spmm_dual64<<<spmmBlocks, 256, 0, stream>>>(rowptrF, packed, hwS, hwC,
                                              b_s2_2, b_c_2, o_emb2, o_com2,
                                              n);

  final_fuse<<<(int)(((long)n * 16 + 255) / 256), 256, 0, stream>>>(
      o_emb1, o_emb2, o_com1, o_com2, attw1, attb1, attw2, mlpw, mlpb, o_logp,
      o_beta, o_emb, n);
}

// Round 14
// 581.294 us; speedup vs baseline: 8.1789x; 1.0980x over previous
//
#include <hip/hip_runtime.h>

// ---------------------------------------------------------------------------
// SFGCN forward on MI355X, round 14 (= round 13 + logits reduce-scatter fix):
//  - final_fuse v3: attention reduce-scatter (lane owns one unit -> 3 tanh)
//    + logits reduce-scatter WITH the missing bit-0 pair exchange
//    (round-13 bug: lanes l, l^1 hold complementary halves, not duplicates).
//  - fused_l1l2_mfma_dual: S-chain + C-chain in one kernel.
//  - counting-sort CSR build, bf16 SpMM, unchanged.
// ---------------------------------------------------------------------------

typedef unsigned short ushort_t;
typedef float f32x4 __attribute__((ext_vector_type(4)));
typedef short short8 __attribute__((ext_vector_type(8)));

#define NBLK1 512  // blocks for coarse hist/scatter (grid-stride)

__device__ __forceinline__ ushort_t f2bf(float f) {  // round-to-nearest-even
  unsigned u = __float_as_uint(f);
  unsigned r = (u + 0x7FFFu + ((u >> 16) & 1u)) >> 16;
  return (ushort_t)r;
}
__device__ __forceinline__ float bf2f(ushort_t b) {
  return __uint_as_float((unsigned)b << 16);
}

// reduce-scatter 16 values across a 16-lane group: lane ends with the full
// 16-lane sum of element [lane&15]. 15 shfl, compile-time register indices.
__device__ __forceinline__ float rs16(const float a[16], int lane) {
  bool b8 = (lane & 8) != 0;
  float t[8];
#pragma unroll
  for (int j = 0; j < 8; ++j) {
    float sent = b8 ? a[j] : a[j + 8];
    float mine = b8 ? a[j + 8] : a[j];
    t[j] = mine + __shfl_xor(sent, 8);
  }
  bool b4 = (lane & 4) != 0;
  float u[4];
#pragma unroll
  for (int j = 0; j < 4; ++j) {
    float sent = b4 ? t[j] : t[j + 4];
    float mine = b4 ? t[j + 4] : t[j];
    u[j] = mine + __shfl_xor(sent, 4);
  }
  bool b2 = (lane & 2) != 0;
  float v[2];
#pragma unroll
  for (int j = 0; j < 2; ++j) {
    float s2 = b2 ? u[j] : u[j + 2];
    float m2 = b2 ? u[j + 2] : u[j];
    v[j] = m2 + __shfl_xor(s2, 2);
  }
  bool b1 = (lane & 1) != 0;
  float s1 = b1 ? v[0] : v[1];
  float m1 = b1 ? v[1] : v[0];
  return m1 + __shfl_xor(s1, 1);
}

// total4 float4 chunks -> ushort4 bf16 chunks
__global__ __launch_bounds__(256) void cvt_bf16(
    const float* __restrict__ in, ushort_t* __restrict__ out, long total4) {
  long i = (long)blockIdx.x * 256 + threadIdx.x;
  if (i >= total4) return;
  float4 v = ((const float4*)in)[i];
  ushort4 o;
  o.x = f2bf(v.x);
  o.y = f2bf(v.y);
  o.z = f2bf(v.z);
  o.w = f2bf(v.w);
  ((ushort4*)out)[i] = o;
}

// Transpose+cast the 3 weight pairs to bf16.
__global__ __launch_bounds__(256) void prep_weights(
    const float* __restrict__ w1a, const float* __restrict__ w1b,
    const float* __restrict__ w1c, const float* __restrict__ w2a,
    const float* __restrict__ w2b, const float* __restrict__ w2c,
    ushort_t* __restrict__ o1a, ushort_t* __restrict__ o1b,
    ushort_t* __restrict__ o1c, ushort_t* __restrict__ o2a,
    ushort_t* __restrict__ o2b, ushort_t* __restrict__ o2c) {
  int i = blockIdx.x * 256 + threadIdx.x;
  if (i < 49152) {  // 3 x 128x128
    int a = i >> 14, j = i & 16383;
    int nn = j >> 7, k = j & 127;
    const float* s = (a == 0) ? w1a : (a == 1) ? w1b : w1c;
    ushort_t* d = (a == 0) ? o1a : (a == 1) ? o1b : o1c;
    d[j] = f2bf(s[k * 128 + nn]);
  } else if (i < 73728) {  // 3 x 64x128
    int i2 = i - 49152;
    int a = i2 >> 13, j = i2 & 8191;
    int h = j >> 7, k = j & 127;
    const float* s = (a == 0) ? w2a : (a == 1) ? w2b : w2c;
    ushort_t* d = (a == 0) ? o2a : (a == 1) ? o2b : o2c;
    d[j] = f2bf(s[k * 64 + h]);
  }
}

// ---------------- two-level counting sort CSR build ----------------

__global__ __launch_bounds__(256) void coarse_hist(
    const int* __restrict__ rowS, const int* __restrict__ rowF,
    int* __restrict__ bkt_cnt, int n, int e, int nb) {
  __shared__ int lh[800];
  int t = threadIdx.x;
  for (int j = t; j < nb; j += 256) lh[j] = 0;
  __syncthreads();
  long total = 2L * e;
  long stride = (long)NBLK1 * 256;
  for (long i = (long)blockIdx.x * 256 + t; i < total; i += stride) {
    int vrow = (i < e) ? rowS[i] : (n + rowF[i - e]);
    atomicAdd(&lh[vrow >> 8], 1);
  }
  __syncthreads();
  for (int j = t; j < nb; j += 256)
    if (lh[j]) atomicAdd(&bkt_cnt[j], lh[j]);
}

__global__ __launch_bounds__(256) void coarse_scan(
    const int* __restrict__ cnt, int* __restrict__ off, int nb, int total) {
  __shared__ int lds[256];
  int t = threadIdx.x;
  int c[4];
  int s = 0;
#pragma unroll
  for (int j = 0; j < 4; ++j) {
    int idx = t * 4 + j;
    c[j] = (idx < nb) ? cnt[idx] : 0;
    s += c[j];
  }
  lds[t] = s;
  __syncthreads();
#pragma unroll
  for (int d = 1; d < 256; d <<= 1) {
    int v = (t >= d) ? lds[t - d] : 0;
    __syncthreads();
    lds[t] += v;
    __syncthreads();
  }
  int o = (t == 0) ? 0 : lds[t - 1];
#pragma unroll
  for (int j = 0; j < 4; ++j) {
    int idx = t * 4 + j;
    if (idx < nb) off[idx] = o;
    o += c[j];
  }
  if (t == 0) off[nb] = total;
}

__global__ __launch_bounds__(256) void coarse_scatter(
    const int* __restrict__ rowS, const int* __restrict__ colS,
    const float* __restrict__ valS, const int* __restrict__ rowF,
    const int* __restrict__ colF, const float* __restrict__ valF,
    const int* __restrict__ bkt_off, int* __restrict__ bkt_woff,
    int2* __restrict__ tmp, int n, int e, int nb) {
  __shared__ int lh[800];
  __shared__ int lb[800];
  __shared__ int gb[800];
  int t = threadIdx.x;
  for (int j = t; j < nb; j += 256) {
    lh[j] = 0;
    lb[j] = 0;
  }
  __syncthreads();
  long total = 2L * e;
  long stride = (long)NBLK1 * 256;
  for (long i = (long)blockIdx.x * 256 + t; i < total; i += stride) {
    int vrow = (i < e) ? rowS[i] : (n + rowF[i - e]);
    atomicAdd(&lh[vrow >> 8], 1);
  }
  __syncthreads();
  for (int j = t; j < nb; j += 256) {
    int h = lh[j];
    gb[j] = h ? (bkt_off[j] + atomicAdd(&bkt_woff[j], h)) : 0;
  }
  __syncthreads();
  for (long i = (long)blockIdx.x * 256 + t; i < total; i += stride) {
    int vrow, c;
    float v;
    if (i < e) {
      vrow = rowS[i];
      c = colS[i];
      v = valS[i];
    } else {
      vrow = n + rowF[i - e];
      c = colF[i - e];
      v = valF[i - e];
    }
    int b = vrow >> 8;
    int k = atomicAdd(&lb[b], 1);
    tmp[gb[b] + k] = make_int2(c | ((vrow & 255) << 24), __float_as_int(v));
  }
}

__global__ __launch_bounds__(256) void fine_sort(
    const int* __restrict__ bkt_off, const int2* __restrict__ tmp,
    int2* __restrict__ packed, int* __restrict__ rowptr, int vtotal,
    int etotal) {
  __shared__ int hist[256];
  __shared__ int scn[256];
  __shared__ int rowb[256];
  __shared__ int bump[256];
  int b = blockIdx.x;
  int t = threadIdx.x;
  int lo = bkt_off[b], hi = bkt_off[b + 1];
  hist[t] = 0;
  bump[t] = 0;
  __syncthreads();
  for (int i = lo + t; i < hi; i += 256)
    atomicAdd(&hist[((unsigned)tmp[i].x) >> 24], 1);
  __syncthreads();
  scn[t] = hist[t];
  __syncthreads();
#pragma unroll
  for (int d = 1; d < 256; d <<= 1) {
    int v = (t >= d) ? scn[t - d] : 0;
    __syncthreads();
    scn[t] += v;
    __syncthreads();
  }
  int rb = lo + ((t == 0) ? 0 : scn[t - 1]);
  rowb[t] = rb;
  int vrow = b * 256 + t;
  if (vrow < vtotal) rowptr[vrow] = rb;
  __syncthreads();
  for (int i = lo + t; i < hi; i += 256) {
    int2 p = tmp[i];
    int vl = ((unsigned)p.x) >> 24;
    int dest = rowb[vl] + atomicAdd(&bump[vl], 1);
    packed[dest] = make_int2(p.x & 0xFFFFFF, p.y);
  }
  if (b == 0 && t == 0) rowptr[vtotal] = etotal;
}

// ---------------- CSR SpMM (bf16 gather, fp32 accumulate) ----------------

__global__ __launch_bounds__(256) void spmm_csr_128(
    const int* __restrict__ rowptr, const int2* __restrict__ packed,
    const ushort_t* __restrict__ h, ushort_t* __restrict__ Ax, int n) {
  int tid = threadIdx.x;
  int r = blockIdx.x * 8 + (tid >> 5);
  if (r >= n) return;
  int lane = tid & 31;
  int lo = rowptr[r], hi = rowptr[r + 1];
  const ushort4* h4 = (const ushort4*)h;  // row stride = 32 ushort4
  float4 acc = make_float4(0.f, 0.f, 0.f, 0.f);
  int e = lo;
  for (; e + 4 <= hi; e += 4) {
    int2 p0 = packed[e], p1 = packed[e + 1], p2 = packed[e + 2],
         p3 = packed[e + 3];
    float v0 = __int_as_float(p0.y), v1 = __int_as_float(p1.y),
          v2 = __int_as_float(p2.y), v3 = __int_as_float(p3.y);
    ushort4 q0 = h4[(long)p0.x * 32 + lane];
    ushort4 q1 = h4[(long)p1.x * 32 + lane];
    ushort4 q2 = h4[(long)p2.x * 32 + lane];
    ushort4 q3 = h4[(long)p3.x * 32 + lane];
    acc.x += v0 * bf2f(q0.x) + v1 * bf2f(q1.x) + v2 * bf2f(q2.x) + v3 * bf2f(q3.x);
    acc.y += v0 * bf2f(q0.y) + v1 * bf2f(q1.y) + v2 * bf2f(q2.y) + v3 * bf2f(q3.y);
    acc.z += v0 * bf2f(q0.z) + v1 * bf2f(q1.z) + v2 * bf2f(q2.z) + v3 * bf2f(q3.z);
    acc.w += v0 * bf2f(q0.w) + v1 * bf2f(q1.w) + v2 * bf2f(q2.w) + v3 * bf2f(q3.w);
  }
  for (; e < hi; ++e) {
    int2 p = packed[e];
    float v = __int_as_float(p.y);
    ushort4 q = h4[(long)p.x * 32 + lane];
    acc.x += v * bf2f(q.x);
    acc.y += v * bf2f(q.y);
    acc.z += v * bf2f(q.z);
    acc.w += v * bf2f(q.w);
  }
  ushort4 o;
  o.x = f2bf(acc.x);
  o.y = f2bf(acc.y);
  o.z = f2bf(acc.z);
  o.w = f2bf(acc.w);
  ((ushort4*)Ax)[(long)r * 32 + lane] = o;
}

__global__ __launch_bounds__(256) void spmm_dual64(
    const int* __restrict__ rowptr, const int2* __restrict__ packed,
    const ushort_t* __restrict__ hS, const ushort_t* __restrict__ hC,
    const float* __restrict__ bS, const float* __restrict__ bC,
    float* __restrict__ outS, float* __restrict__ outC, int n) {
  int tid = threadIdx.x;
  int r = blockIdx.x * 8 + (tid >> 5);
  if (r >= n) return;
  int lane = tid & 31;
  int half = lane >> 4;
  int li = lane & 15;
  const ushort4* h4 = (const ushort4*)(half ? hC : hS);  // row = 16 ushort4
  float4 acc = ((const float4*)(half ? bC : bS))[li];
  int lo = rowptr[r], hi = rowptr[r + 1];
  int e = lo;
  for (; e + 4 <= hi; e += 4) {
    int2 p0 = packed[e], p1 = packed[e + 1], p2 = packed[e + 2],
         p3 = packed[e + 3];
    float v0 = __int_as_float(p0.y), v1 = __int_as_float(p1.y),
          v2 = __int_as_float(p2.y), v3 = __int_as_float(p3.y);
    ushort4 q0 = h4[(long)p0.x * 16 + li];
    ushort4 q1 = h4[(long)p1.x * 16 + li];
    ushort4 q2 = h4[(long)p2.x * 16 + li];
    ushort4 q3 = h4[(long)p3.x * 16 + li];
    acc.x += v0 * bf2f(q0.x) + v1 * bf2f(q1.x) + v2 * bf2f(q2.x) + v3 * bf2f(q3.x);
    acc.y += v0 * bf2f(q0.y) + v1 * bf2f(q1.y) + v2 * bf2f(q2.y) + v3 * bf2f(q3.y);
    acc.z += v0 * bf2f(q0.z) + v1 * bf2f(q1.z) + v2 * bf2f(q2.z) + v3 * bf2f(q3.z);
    acc.w += v0 * bf2f(q0.w) + v1 * bf2f(q1.w) + v2 * bf2f(q2.w) + v3 * bf2f(q3.w);
  }
  for (; e < hi; ++e) {
    int2 p = packed[e];
    float v = __int_as_float(p.y);
    ushort4 q = h4[(long)p.x * 16 + li];
    acc.x += v * bf2f(q.x);
    acc.y += v * bf2f(q.y);
    acc.z += v * bf2f(q.z);
    acc.w += v * bf2f(q.w);
  }
  float4* o = (float4*)(half ? outC : outS);
  o[(long)r * 16 + li] = acc;
}

// ---------------- fused dense chain, bf16 MFMA, dual weight sets ----------
__device__ __forceinline__ void l1l2_chain(
    const ushort_t* __restrict__ Ax, const ushort_t* __restrict__ W1T,
    const float* __restrict__ B1, const ushort_t* __restrict__ W2T,
    ushort_t* __restrict__ H, int n, long node0, int w, int lo16, int g,
    ushort_t (*sp)[136]) {
  // ---- GEMM1 (flipped): S^T = W1T x Ax^T ----
  f32x4 acc1[2][4];
#pragma unroll
  for (int m = 0; m < 2; ++m)
#pragma unroll
    for (int nu = 0; nu < 4; ++nu) acc1[m][nu] = (f32x4){0.f, 0.f, 0.f, 0.f};

#pragma unroll 1
  for (int t = 0; t < 4; ++t) {
    short8 af0 = *(const short8*)(W1T + (32 * w + lo16) * 128 + 32 * t + 8 * g);
    short8 af1 =
        *(const short8*)(W1T + (32 * w + 16 + lo16) * 128 + 32 * t + 8 * g);
#pragma unroll
    for (int nu = 0; nu < 4; ++nu) {
      long node = node0 + 16 * nu + lo16;
      if (node > (long)n - 1) node = (long)n - 1;
      short8 bf = *(const short8*)(Ax + node * 128 + 32 * t + 8 * g);
      acc1[0][nu] =
          __builtin_amdgcn_mfma_f32_16x16x32_bf16(af0, bf, acc1[0][nu], 0, 0, 0);
      acc1[1][nu] =
          __builtin_amdgcn_mfma_f32_16x16x32_bf16(af1, bf, acc1[1][nu], 0, 0, 0);
    }
  }

  // relu + bias, pack 4 contiguous sfeats -> S' LDS
#pragma unroll
  for (int m = 0; m < 2; ++m) {
    int sf = 32 * w + 16 * m + 4 * g;
    float4 b1v = *(const float4*)(B1 + sf);
#pragma unroll
    for (int nu = 0; nu < 4; ++nu) {
      int node_l = 16 * nu + lo16;
      ushort4 pk;
      pk.x = f2bf(fmaxf(acc1[m][nu][0] + b1v.x, 0.f));
      pk.y = f2bf(fmaxf(acc1[m][nu][1] + b1v.y, 0.f));
      pk.z = f2bf(fmaxf(acc1[m][nu][2] + b1v.z, 0.f));
      pk.w = f2bf(fmaxf(acc1[m][nu][3] + b1v.w, 0.f));
      *(ushort4*)(&sp[node_l][sf]) = pk;
    }
  }
  __syncthreads();

  // ---- GEMM2 (standard): H = S' @ W2 ----
  f32x4 acc2[4];
#pragma unroll
  for (int nu = 0; nu < 4; ++nu) acc2[nu] = (f32x4){0.f, 0.f, 0.f, 0.f};
#pragma unroll 1
  for (int t = 0; t < 4; ++t) {
    short8 af = *(const short8*)(&sp[16 * w + lo16][32 * t + 8 * g]);
#pragma unroll
    for (int nu = 0; nu < 4; ++nu) {
      short8 bf =
          *(const short8*)(W2T + (16 * nu + lo16) * 128 + 32 * t + 8 * g);
      acc2[nu] =
          __builtin_amdgcn_mfma_f32_16x16x32_bf16(af, bf, acc2[nu], 0, 0, 0);
    }
  }
#pragma unroll
  for (int nu = 0; nu < 4; ++nu) {
#pragma unroll
    for (int r = 0; r < 4; ++r) {
      long node = node0 + 16 * w + 4 * g + r;
      if (node < n) H[node * 64 + 16 * nu + lo16] = f2bf(acc2[nu][r]);
    }
  }
}

__global__ __launch_bounds__(256) void fused_l1l2_mfma_dual(
    const ushort_t* __restrict__ Ax, const ushort_t* __restrict__ W1Ta,
    const float* __restrict__ B1a, const ushort_t* __restrict__ W2Ta,
    ushort_t* __restrict__ Ha, const ushort_t* __restrict__ W1Tb,
    const float* __restrict__ B1b, const ushort_t* __restrict__ W2Tb,
    ushort_t* __restrict__ Hb, int n) {
  __shared__ __attribute__((aligned(16))) ushort_t sp[64][136];
  int tid = threadIdx.x;
  int w = tid >> 6;
  int l = tid & 63;
  int lo16 = l & 15;
  int g = l >> 4;
  long node0 = (long)blockIdx.x * 64;

  l1l2_chain(Ax, W1Ta, B1a, W2Ta, Ha, n, node0, w, lo16, g, sp);
  __syncthreads();  // WAR on sp before chain B overwrites
  l1l2_chain(Ax, W1Tb, B1b, W2Tb, Hb, n, node0, w, lo16, g, sp);
}

// ---------------- final fuse v3 (reduce-scatter; 16 lanes per node) -------
__global__ __launch_bounds__(256) void final_fuse(
    const float* __restrict__ emb1, const float* __restrict__ emb2,
    const float* __restrict__ com1, const float* __restrict__ com2,
    const float* __restrict__ attw1, const float* __restrict__ attb1,
    const float* __restrict__ attw2, const float* __restrict__ mlpw,
    const float* __restrict__ mlpb, float* __restrict__ out_logp,
    float* __restrict__ out_beta, float* __restrict__ out_emb, int n) {
  __shared__ __attribute__((aligned(16))) float w1t[16][64];
  __shared__ __attribute__((aligned(16))) float mwt[8][64];
  __shared__ float b1s[16];
  __shared__ float w2s[16];
  __shared__ float mbs[8];
  int tid = threadIdx.x;
  for (int idx = tid; idx < 1024; idx += 256)
    w1t[idx & 15][idx >> 4] = attw1[idx];
  for (int idx = tid; idx < 512; idx += 256)
    mwt[idx & 7][idx >> 3] = mlpw[idx];
  if (tid < 16) {
    b1s[tid] = attb1[tid];
    w2s[tid] = attw2[tid];
  }
  if (tid < 8) mbs[tid] = mlpb[tid];
  __syncthreads();

  int lane = tid & 15;
  long i = ((long)blockIdx.x * 256 + tid) >> 4;
  bool alive = i < n;
  long ii = alive ? i : (long)(n - 1);

  float4 z0 = ((const float4*)emb1)[ii * 16 + lane];
  float4 z1 = ((const float4*)emb2)[ii * 16 + lane];
  float4 x1 = ((const float4*)com1)[ii * 16 + lane];
  float4 x2 = ((const float4*)com2)[ii * 16 + lane];
  float4 z2 = make_float4(0.5f * (x1.x + x2.x), 0.5f * (x1.y + x2.y),
                          0.5f * (x1.z + x2.z), 0.5f * (x1.w + x2.w));

  // attention partials
  float a0[16], a1[16], a2[16];
#pragma unroll
  for (int m = 0; m < 16; ++m) {
    float4 w = *(const float4*)&w1t[m][lane * 4];
    a0[m] = z0.x * w.x + z0.y * w.y + z0.z * w.z + z0.w * w.w;
    a1[m] = z1.x * w.x + z1.y * w.y + z1.z * w.z + z1.w * w.w;
    a2[m] = z2.x * w.x + z2.y * w.y + z2.z * w.z + z2.w * w.w;
  }
  // reduce-scatter: lane owns unit m = lane
  float A0 = rs16(a0, lane);
  float A1 = rs16(a1, lane);
  float A2 = rs16(a2, lane);
  // per-lane tanh (3 instead of 48), then all-reduce of the 3 scores
  float bm = b1s[lane], wm = w2s[lane];
  float p0 = tanhf(A0 + bm) * wm;
  float p1 = tanhf(A1 + bm) * wm;
  float p2 = tanhf(A2 + bm) * wm;
#pragma unroll
  for (int d = 1; d < 16; d <<= 1) {
    p0 += __shfl_xor(p0, d);
    p1 += __shfl_xor(p1, d);
    p2 += __shfl_xor(p2, d);
  }
  float mx = fmaxf(p0, fmaxf(p1, p2));
  float ex0 = expf(p0 - mx), ex1 = expf(p1 - mx), ex2 = expf(p2 - mx);
  float inv = 1.f / (ex0 + ex1 + ex2);
  float be0 = ex0 * inv, be1 = ex1 * inv, be2 = ex2 * inv;

  float4 em;
  em.x = be0 * z0.x + be1 * z1.x + be2 * z2.x;
  em.y = be0 * z0.y + be1 * z1.y + be2 * z2.y;
  em.z = be0 * z0.z + be1 * z1.z + be2 * z2.z;
  em.w = be0 * z0.w + be1 * z1.w + be2 * z2.w;
  if (alive) ((float4*)out_emb)[i * 16 + lane] = em;

  // logits partials
  float lg[8];
#pragma unroll
  for (int p = 0; p < 8; ++p) {
    float4 w = *(const float4*)&mwt[p][lane * 4];
    lg[p] = em.x * w.x + em.y * w.y + em.z * w.z + em.w * w.w;
  }
  // reduce-scatter 8 elements over 16 lanes; owner index = 4*b8 + 2*b4 + b2,
  // then the bit-0 pair exchange completes the 16-lane sum (round-13 bugfix).
  bool b8 = (lane & 8) != 0;
  float t4[4];
#pragma unroll
  for (int j = 0; j < 4; ++j) {
    float sent = b8 ? lg[j] : lg[j + 4];
    float mine = b8 ? lg[j + 4] : lg[j];
    t4[j] = mine + __shfl_xor(sent, 8);
  }
  bool b4 = (lane & 4) != 0;
  float t2[2];
#pragma unroll
  for (int j = 0; j < 2; ++j) {
    float sent = b4 ? t4[j] : t4[j + 2];
    float mine = b4 ? t4[j + 2] : t4[j];
    t2[j] = mine + __shfl_xor(sent, 4);
  }
  bool b2 = (lane & 2) != 0;
  {
    float sent = b2 ? t2[0] : t2[1];
    float mine = b2 ? t2[1] : t2[0];
    t2[0] = mine + __shfl_xor(sent, 2);
  }
  t2[0] += __shfl_xor(t2[0], 1);  // <-- bugfix: lanes l, l^1 hold halves
  int myidx = (b8 ? 4 : 0) + (b4 ? 2 : 0) + (b2 ? 1 : 0);
  float lgv = t2[0] + mbs[myidx];
  // all-reduce max & sum over the 8 distinct indices (d = 2,4,8)
  float m2 = lgv;
  m2 = fmaxf(m2, __shfl_xor(m2, 2));
  m2 = fmaxf(m2, __shfl_xor(m2, 4));
  m2 = fmaxf(m2, __shfl_xor(m2, 8));
  float ev = expf(lgv - m2);
  float ssum = ev;
  ssum += __shfl_xor(ssum, 2);
  ssum += __shfl_xor(ssum, 4);
  ssum += __shfl_xor(ssum, 8);
  float ls = m2 + logf(ssum);

  if (alive) {
    if ((lane & 1) == 0) out_logp[i * 8 + myidx] = lgv - ls;
    if (lane == 0) {
      out_beta[i * 3 + 0] = be0;
      out_beta[i * 3 + 1] = be1;
      out_beta[i * 3 + 2] = be2;
    }
  }
}

extern "C" void kernel_launch(void* const* d_in, const int* in_sizes, int n_in,
                              void* d_out, int out_size, void* d_ws,
                              size_t ws_size, hipStream_t stream) {
  const float* x = (const float*)d_in[0];
  const int* srow = (const int*)d_in[1];
  const int* scol_in = (const int*)d_in[2];
  const float* sval_in = (const float*)d_in[3];
  const int* frow = (const int*)d_in[4];
  const int* fcol_in = (const int*)d_in[5];
  const float* fval_in = (const float*)d_in[6];
  const float* w_s1_1 = (const float*)d_in[7];
  const float* b_s1_1 = (const float*)d_in[8];
  const float* w_s1_2 = (const float*)d_in[9];
  const float* b_s1_2 = (const float*)d_in[10];
  const float* w_s2_1 = (const float*)d_in[11];
  const float* b_s2_1 = (const float*)d_in[12];
  const float* w_s2_2 = (const float*)d_in[13];
  const float* b_s2_2 = (const float*)d_in[14];
  const float* w_c_1 = (const float*)d_in[15];
  const float* b_c_1 = (const float*)d_in[16];
  const float* w_c_2 = (const float*)d_in[17];
  const float* b_c_2 = (const float*)d_in[18];
  const float* attw1 = (const float*)d_in[19];
  const float* attb1 = (const float*)d_in[20];
  const float* attw2 = (const float*)d_in[21];
  const float* mlpw = (const float*)d_in[22];
  const float* mlpb = (const float*)d_in[23];

  const int n = in_sizes[0] / 128;  // 100000
  const int e = in_sizes[1];        // 1600000
  const int vtotal = 2 * n;
  const int nb = (vtotal + 255) >> 8;  // 782 coarse buckets

  float* out = (float*)d_out;
  float* o_logp = out;
  float* o_beta = out + (size_t)n * 8;
  float* o_emb1 = out + (size_t)n * 11;
  float* o_com1 = o_emb1 + (size_t)n * 64;
  float* o_com2 = o_com1 + (size_t)n * 64;
  float* o_emb2 = o_com2 + (size_t)n * 64;
  float* o_emb = o_emb2 + (size_t)n * 64;

  // x_bf16 in o_emb region (25.6MB, exact fit); overwritten by final_fuse.
  ushort_t* x_bf16 = (ushort_t*)o_emb;
  // tmp (coarse-bucketed edges) in o_emb1 region: consumed by fine_sort
  // before spmm_dual64 writes o_emb1.
  int2* tmp = (int2*)o_emb1;

  // workspace layout (~78MB)
  ushort_t* ax = (ushort_t*)d_ws;                 // n*128 bf16
  ushort_t* hwS = ax + (size_t)n * 128;           // n*64 bf16
  ushort_t* hwC = hwS + (size_t)n * 64;           // n*64 bf16
  ushort_t* w1t_s1 = hwC + (size_t)n * 64;        // 128*128 bf16
  ushort_t* w1t_s2 = w1t_s1 + 16384;
  ushort_t* w1t_c = w1t_s2 + 16384;
  ushort_t* w2t_s1 = w1t_c + 16384;               // 64*128 bf16
  ushort_t* w2t_s2 = w2t_s1 + 8192;
  ushort_t* w2t_c = w2t_s2 + 8192;
  int* rowptr = (int*)(w2t_c + 8192);             // 2n+1
  int* bkt_cnt = rowptr + vtotal + 1;             // nb
  int* bkt_woff = bkt_cnt + nb;                   // nb
  int* bkt_off = bkt_woff + nb;                   // nb+1
  int* tail = bkt_off + nb + 2;                   // align to 8B for int2
  int2* packed = (int2*)(tail + ((((size_t)(tail)&7) == 0) ? 0 : 1));

  const int spmmBlocks = (n + 7) / 8;
  const int cvtBlocks = (int)(((long)n * 32 + 255) / 256);
  const int mfmaBlocks = (n + 63) / 64;

  // one-time preprocessing
  cvt_bf16<<<cvtBlocks, 256, 0, stream>>>(x, x_bf16, (long)n * 32);
  prep_weights<<<288, 256, 0, stream>>>(w_s1_1, w_s2_1, w_c_1, w_s1_2, w_s2_2,
                                        w_c_2, w1t_s1, w1t_s2, w1t_c, w2t_s1,
                                        w2t_s2, w2t_c);

  // two-level counting-sort CSR build (both graphs at once)
  hipMemsetAsync(bkt_cnt, 0, (size_t)(2 * nb) * sizeof(int), stream);
  coarse_hist<<<NBLK1, 256, 0, stream>>>(srow, frow, bkt_cnt, n, e, nb);
  coarse_scan<<<1, 256, 0, stream>>>(bkt_cnt, bkt_off, nb, 2 * e);
  coarse_scatter<<<NBLK1, 256, 0, stream>>>(srow, scol_in, sval_in, frow,
                                            fcol_in, fval_in, bkt_off,
                                            bkt_woff, tmp, n, e, nb);
  fine_sort<<<nb, 256, 0, stream>>>(bkt_off, tmp, packed, rowptr, vtotal,
                                    2 * e);

  const int* rowptrS = rowptr;      // sadj rows: rowptr[0..n]
  const int* rowptrF = rowptr + n;  // fadj rows: rowptr[n..2n]

  // --- graph sadj: emb1 (w_s1) + com1 (w_c) ---
  spmm_csr_128<<<spmmBlocks, 256, 0, stream>>>(rowptrS, packed, x_bf16, ax, n);
  fused_l1l2_mfma_dual<<<mfmaBlocks, 256, 0, stream>>>(
      ax, w1t_s1, b_s1_1, w2t_s1, hwS, w1t_c, b_c_1, w2t_c, hwC, n);
  spmm_dual64<<<spmmBlocks, 256, 0, stream>>>(rowptrS, packed, hwS, hwC,
                                              b_s1_2, b_c_2, o_emb1, o_com1,
                                              n);

  // --- graph fadj: com2 (w_c) + emb2 (w_s2) ---
  spmm_csr_128<<<spmmBlocks, 256, 0, stream>>>(rowptrF, packed, x_bf16, ax, n);
  fused_l1l2_mfma_dual<<<mfmaBlocks, 256, 0, stream>>>(
      ax, w1t_s2, b_s2_1, w2t_s2, hwS, w1t_c, b_c_1, w2t_c, hwC, n);
  spmm_dual64<<<spmmBlocks, 256, 0, stream>>>(rowptrF, packed, hwS, hwC,
                                              b_s2_2, b_c_2, o_emb2, o_com2,
                                              n);

  final_fuse<<<(int)(((long)n * 16 + 255) / 256), 256, 0, stream>>>(
      o_emb1, o_emb2, o_com1, o_com2, attw1, attb1, attw2, mlpw, mlpb, o_logp,
      o_beta, o_emb, n);
}